// Round 5
// baseline (413.859 us; speedup 1.0000x reference)
//
#include <hip/hip_runtime.h>
#include <math.h>

#define NNODES 50000
#define NEDGES 400000
#define INC    128
#define HC1    256   // HEADS*HID
#define NHEADS 8
#define OUTC   64
#define NK     16
#define NEG_SLOPE 0.2f
#define EPS_F  1e-16f

typedef unsigned short u16;
typedef __attribute__((ext_vector_type(8))) short bf16x8;
typedef __attribute__((ext_vector_type(4))) float f32x4;

__device__ __forceinline__ float lrelu(float x){ return x > 0.f ? x : NEG_SLOPE * x; }
__device__ __forceinline__ float eluf(float x){ return x > 0.f ? x : (expf(x) - 1.f); }
__device__ __forceinline__ float bf2f(u16 v){ return __uint_as_float((unsigned)v << 16); }
__device__ __forceinline__ u16 f2bf(float f){
    unsigned u = __float_as_uint(f);
    unsigned r = (u + 0x7FFFu + ((u >> 16) & 1u)) >> 16;   // RTNE
    return (u16)r;
}

// ---------------- CSR build ----------------
__global__ void count_deg_k(const int* __restrict__ dst, int* __restrict__ deg){
    int e = blockIdx.x * 256 + threadIdx.x;
    if (e < NEDGES) atomicAdd(&deg[dst[e]], 1);
}

__global__ void blocksum_k(const int* __restrict__ deg, int* __restrict__ bsum){
    __shared__ int sm[4];
    int i = blockIdx.x * 256 + threadIdx.x;
    int v = (i < NNODES) ? deg[i] : 0;
    for (int off = 1; off < 64; off <<= 1) v += __shfl_xor(v, off);
    int lane = threadIdx.x & 63, wid = threadIdx.x >> 6;
    if (lane == 0) sm[wid] = v;
    __syncthreads();
    if (threadIdx.x == 0) bsum[blockIdx.x] = sm[0] + sm[1] + sm[2] + sm[3];
}

__global__ void scan_bsum_k(const int* __restrict__ bsum, int* __restrict__ boff, int nb){
    int tid = threadIdx.x;
    int v = (tid < nb) ? bsum[tid] : 0;
    int orig = v;
    int lane = tid & 63, wid = tid >> 6;
    for (int off = 1; off < 64; off <<= 1){ int t = __shfl_up(v, off); if (lane >= off) v += t; }
    __shared__ int wsum[4];
    if (lane == 63) wsum[wid] = v;
    __syncthreads();
    int add = 0;
    for (int w = 0; w < wid; w++) add += wsum[w];
    v += add;
    if (tid < nb) boff[tid] = v - orig;
}

__global__ void scan_write_k(const int* __restrict__ deg, const int* __restrict__ boff,
                             int* __restrict__ rowptr){
    int tid = threadIdx.x;
    int i = blockIdx.x * 256 + tid;
    int v = (i < NNODES) ? deg[i] : 0;
    int lane = tid & 63, wid = tid >> 6;
    int sv = v;
    for (int off = 1; off < 64; off <<= 1){ int t = __shfl_up(sv, off); if (lane >= off) sv += t; }
    __shared__ int wsum[4];
    if (lane == 63) wsum[wid] = sv;
    __syncthreads();
    int add = 0;
    for (int w = 0; w < wid; w++) add += wsum[w];
    sv += add;
    if (i < NNODES) rowptr[i + 1] = boff[blockIdx.x] + sv;
    if (i == 0) rowptr[0] = 0;
}

__global__ void fill_csr_k(const int* __restrict__ src, const int* __restrict__ dst,
                           const int* __restrict__ rowptr, int* __restrict__ fillc,
                           int* __restrict__ col){
    int e = blockIdx.x * 256 + threadIdx.x;
    if (e < NEDGES){
        int d = dst[e];
        int pos = atomicAdd(&fillc[d], 1);
        col[rowptr[d] + pos] = src[e];
    }
}

// ---------------- casts / transposes ----------------
__global__ void cast_x_k(const float* __restrict__ x, u16* __restrict__ xb){
    int i = (blockIdx.x * 256 + threadIdx.x) * 4;   // NNODES*INC = 6.4M, divisible
    float4 v = *(const float4*)(x + i);
    ushort4 o = make_ushort4(f2bf(v.x), f2bf(v.y), f2bf(v.z), f2bf(v.w));
    *(ushort4*)(xb + i) = o;
}

// W1 [128,256] fp32 -> W1t [256,128] bf16
__global__ void transpose_w1_k(const float* __restrict__ W, u16* __restrict__ Wt){
    int i = blockIdx.x * 256 + threadIdx.x;   // 32768
    int n = i >> 7, k = i & 127;
    Wt[i] = f2bf(W[k * 256 + n]);
}

// W2 [256,64] fp32 -> W2t [64,256] bf16
__global__ void transpose_w2_k(const float* __restrict__ W, u16* __restrict__ Wt){
    int i = blockIdx.x * 256 + threadIdx.x;   // 16384
    int n = i >> 8, k = i & 255;
    Wt[i] = f2bf(W[k * 64 + n]);
}

// ---------------- MFMA GEMM 1: h1b[N,256] = xb[N,128] @ W1 (bf16 in/out, fp32 acc) ----------------
// one wave = one 16x16 C tile; A frag: [m=lane&15][k=quad*8+j]; B frag from W1t (row n, contig k)
__global__ void gemm1_mfma_k(const u16* __restrict__ xb, const u16* __restrict__ W1t,
                             u16* __restrict__ h1b){
    int lane = threadIdx.x & 63, wid = threadIdx.x >> 6;
    int ln = lane & 15, quad = lane >> 4;
    int m0 = (blockIdx.x * 4 + wid) * 16;
    int n0 = blockIdx.y * 16;
    int arow = m0 + ln; if (arow >= NNODES) arow = NNODES - 1;
    f32x4 acc = {0.f, 0.f, 0.f, 0.f};
#pragma unroll
    for (int kt = 0; kt < 4; kt++){
        bf16x8 a = *(const bf16x8*)(xb  + (size_t)arow * INC      + kt * 32 + quad * 8);
        bf16x8 b = *(const bf16x8*)(W1t + (size_t)(n0 + ln) * INC + kt * 32 + quad * 8);
        acc = __builtin_amdgcn_mfma_f32_16x16x32_bf16(a, b, acc, 0, 0, 0);
    }
#pragma unroll
    for (int i = 0; i < 4; i++){
        int r = m0 + quad * 4 + i;
        if (r < NNODES) h1b[(size_t)r * HC1 + n0 + ln] = f2bf(acc[i]);
    }
}

// ---------------- MFMA GEMM 2: h2b[N,64] = hL1b[N,256] @ W2 ----------------
__global__ void gemm2_mfma_k(const u16* __restrict__ hL1b, const u16* __restrict__ W2t,
                             u16* __restrict__ h2b){
    int lane = threadIdx.x & 63, wid = threadIdx.x >> 6;
    int ln = lane & 15, quad = lane >> 4;
    int m0 = (blockIdx.x * 4 + wid) * 16;
    int n0 = blockIdx.y * 16;
    int arow = m0 + ln; if (arow >= NNODES) arow = NNODES - 1;
    f32x4 acc = {0.f, 0.f, 0.f, 0.f};
#pragma unroll
    for (int kt = 0; kt < 8; kt++){
        bf16x8 a = *(const bf16x8*)(hL1b + (size_t)arow * HC1      + kt * 32 + quad * 8);
        bf16x8 b = *(const bf16x8*)(W2t  + (size_t)(n0 + ln) * HC1 + kt * 32 + quad * 8);
        acc = __builtin_amdgcn_mfma_f32_16x16x32_bf16(a, b, acc, 0, 0, 0);
    }
#pragma unroll
    for (int i = 0; i < 4; i++){
        int r = m0 + quad * 4 + i;
        if (r < NNODES) h2b[(size_t)r * OUTC + n0 + ln] = f2bf(acc[i]);
    }
}

// ---------------- attention scores (bf16 inputs) ----------------
__global__ void att1_k(const u16* __restrict__ h1b, const float* __restrict__ att_s,
                       const float* __restrict__ att_d,
                       float* __restrict__ as1, float* __restrict__ ad1){
    int lane = threadIdx.x & 63, wid = threadIdx.x >> 6;
    int n = blockIdx.x * 4 + wid;
    ushort4 u = *(const ushort4*)(h1b + (size_t)n * HC1 + lane * 4);
    float4 hv = make_float4(bf2f(u.x), bf2f(u.y), bf2f(u.z), bf2f(u.w));
    float4 sv = *(const float4*)(att_s + lane * 4);
    float4 dv = *(const float4*)(att_d + lane * 4);
    float ps = hv.x * sv.x + hv.y * sv.y + hv.z * sv.z + hv.w * sv.w;
    float pd = hv.x * dv.x + hv.y * dv.y + hv.z * dv.z + hv.w * dv.w;
    for (int m = 1; m < 8; m <<= 1){ ps += __shfl_xor(ps, m); pd += __shfl_xor(pd, m); }
    if ((lane & 7) == 0){
        int h = lane >> 3;
        as1[n * NHEADS + h] = ps;
        ad1[n * NHEADS + h] = pd;
    }
}

__global__ void att2_k(const u16* __restrict__ h2b, const float* __restrict__ att_s,
                       const float* __restrict__ att_d,
                       float* __restrict__ as2, float* __restrict__ ad2){
    int lane = threadIdx.x & 63, wid = threadIdx.x >> 6;
    int n = blockIdx.x * 4 + wid;
    float hv = bf2f(h2b[(size_t)n * OUTC + lane]);
    float ps = hv * att_s[lane];
    float pd = hv * att_d[lane];
    for (int m = 1; m < 64; m <<= 1){ ps += __shfl_xor(ps, m); pd += __shfl_xor(pd, m); }
    if (lane == 0){ as2[n] = ps; ad2[n] = pd; }
}

// ---------------- GAT layer 1 aggregation (R3 version, known-good) ----------------
__global__ void gat1_agg_k(const u16* __restrict__ h1b, const float* __restrict__ as1,
                           const float* __restrict__ ad1, const int* __restrict__ rowptr,
                           const int* __restrict__ col, const float* __restrict__ b1,
                           u16* __restrict__ outb){
    int lane = threadIdx.x & 63, wid = threadIdx.x >> 6;
    int d = blockIdx.x * 4 + wid;
    int row0 = rowptr[d];
    int deg  = rowptr[d + 1] - row0;

    int h8 = lane & 7, j = lane >> 3;
    float adst      = ad1[d * NHEADS + h8];
    float asrc_self = as1[d * NHEADS + h8];
    float e_self = lrelu(asrc_self + adst);

    float vmax = e_self;
    for (int base = 0; base < deg; base += 8){
        int idx = base + j;
        if (idx < deg){
            int s = col[row0 + idx];
            vmax = fmaxf(vmax, lrelu(as1[s * NHEADS + h8] + adst));
        }
    }
    vmax = fmaxf(vmax, __shfl_xor(vmax, 8));
    vmax = fmaxf(vmax, __shfl_xor(vmax, 16));
    vmax = fmaxf(vmax, __shfl_xor(vmax, 32));

    float vsum = (j == 0) ? expf(e_self - vmax) : 0.f;
    for (int base = 0; base < deg; base += 8){
        int idx = base + j;
        if (idx < deg){
            int s = col[row0 + idx];
            vsum += expf(lrelu(as1[s * NHEADS + h8] + adst) - vmax);
        }
    }
    vsum += __shfl_xor(vsum, 8);
    vsum += __shfl_xor(vsum, 16);
    vsum += __shfl_xor(vsum, 32);
    float den = vsum + EPS_F;

    int hc = lane >> 3;
    float m_c    = __shfl(vmax, hc);
    float rden_c = 1.f / __shfl(den, hc);
    float adst_c = __shfl(adst, hc);
    float asrc_d = __shfl(asrc_self, hc);
    int cbase = lane * 4;

    float alpha = expf(lrelu(asrc_d + adst_c) - m_c) * rden_c;  // self-loop
    ushort4 us = *(const ushort4*)(h1b + (size_t)d * HC1 + cbase);
    float4 acc = make_float4(alpha * bf2f(us.x), alpha * bf2f(us.y),
                             alpha * bf2f(us.z), alpha * bf2f(us.w));

    for (int idx = 0; idx < deg; idx++){
        int s = col[row0 + idx];
        float a = expf(lrelu(as1[s * NHEADS + hc] + adst_c) - m_c) * rden_c;
        ushort4 u4 = *(const ushort4*)(h1b + (size_t)s * HC1 + cbase);
        acc.x += a * bf2f(u4.x); acc.y += a * bf2f(u4.y);
        acc.z += a * bf2f(u4.z); acc.w += a * bf2f(u4.w);
    }
    float4 bb = *(const float4*)(b1 + cbase);
    ushort4 ob = make_ushort4(f2bf(eluf(acc.x + bb.x)), f2bf(eluf(acc.y + bb.y)),
                              f2bf(eluf(acc.z + bb.z)), f2bf(eluf(acc.w + bb.w)));
    *(ushort4*)(outb + (size_t)d * HC1 + cbase) = ob;
}

// ---------------- GAT layer 2 aggregation (R3 version, known-good) ----------------
__global__ void gat2_agg_k(const u16* __restrict__ h2b, const float* __restrict__ as2,
                           const float* __restrict__ ad2, const int* __restrict__ rowptr,
                           const int* __restrict__ col, const float* __restrict__ b2,
                           float* __restrict__ emb){
    int lane = threadIdx.x & 63, wid = threadIdx.x >> 6;
    int d = blockIdx.x * 4 + wid;
    int row0 = rowptr[d];
    int deg  = rowptr[d + 1] - row0;

    float adst = ad2[d];
    float e_self = lrelu(as2[d] + adst);
    float vmax = e_self;
    for (int base = 0; base < deg; base += 64){
        int idx = base + lane;
        if (idx < deg){
            int s = col[row0 + idx];
            vmax = fmaxf(vmax, lrelu(as2[s] + adst));
        }
    }
    for (int m = 1; m < 64; m <<= 1) vmax = fmaxf(vmax, __shfl_xor(vmax, m));

    float vsum = (lane == 0) ? expf(e_self - vmax) : 0.f;
    for (int base = 0; base < deg; base += 64){
        int idx = base + lane;
        if (idx < deg){
            int s = col[row0 + idx];
            vsum += expf(lrelu(as2[s] + adst) - vmax);
        }
    }
    for (int m = 1; m < 64; m <<= 1) vsum += __shfl_xor(vsum, m);
    float rden = 1.f / (vsum + EPS_F);

    float alpha = expf(e_self - vmax) * rden;
    float acc = alpha * bf2f(h2b[(size_t)d * OUTC + lane]);
    for (int idx = 0; idx < deg; idx++){
        int s = col[row0 + idx];
        float a = expf(lrelu(as2[s] + adst) - vmax) * rden;
        acc += a * bf2f(h2b[(size_t)s * OUTC + lane]);
    }
    emb[(size_t)d * OUTC + lane] = acc + b2[lane];
}

// ---------------- MLP head + softmax: LDS-resident weights, 4 nodes/wave ----------------
__global__ __launch_bounds__(256, 2) void mlp_k(const float* __restrict__ emb,
                      const float* __restrict__ Wm1, const float* __restrict__ bm1,
                      const float* __restrict__ Wm2, const float* __restrict__ bm2,
                      float* __restrict__ sout){
    __shared__ float W1a[64][64];
    __shared__ float W1b[64][64];
    __shared__ float W2t[16][132];
    __shared__ float b1s[128];
    __shared__ float b2s[16];
    __shared__ float semb[4][64][4];
    __shared__ float shid[4][4][132];

    int tx = threadIdx.x;
    for (int i = tx; i < 64 * 64; i += 256){
        int c = i >> 6, l = i & 63;
        W1a[c][l] = Wm1[c * 128 + l];
        W1b[c][l] = Wm1[c * 128 + 64 + l];
    }
    for (int i = tx; i < 16 * 128; i += 256){
        int k = i >> 7, j = i & 127;
        W2t[k][j] = Wm2[j * NK + k];
    }
    if (tx < 128) b1s[tx] = bm1[tx];
    if (tx < 16)  b2s[tx] = bm2[tx];
    __syncthreads();

    int lane = tx & 63, wid = tx >> 6;
    int k16 = lane & 15, ni = lane >> 4;

    for (int base = blockIdx.x * 16; base < NNODES; base += gridDim.x * 16){
        int d0 = base + wid * 4;
#pragma unroll
        for (int i = 0; i < 4; i++)
            semb[wid][lane][i] = emb[(size_t)(d0 + i) * OUTC + lane];
        __syncthreads();

        float2 acc[4];
#pragma unroll
        for (int i = 0; i < 4; i++) acc[i] = make_float2(b1s[lane], b1s[64 + lane]);
#pragma unroll 8
        for (int c = 0; c < 64; c++){
            float wa = W1a[c][lane];
            float wb = W1b[c][lane];
            float4 e = *(const float4*)&semb[wid][c][0];
            acc[0].x += e.x * wa; acc[0].y += e.x * wb;
            acc[1].x += e.y * wa; acc[1].y += e.y * wb;
            acc[2].x += e.z * wa; acc[2].y += e.z * wb;
            acc[3].x += e.w * wa; acc[3].y += e.w * wb;
        }
#pragma unroll
        for (int i = 0; i < 4; i++){
            shid[wid][i][lane]      = fmaxf(acc[i].x, 0.f);
            shid[wid][i][64 + lane] = fmaxf(acc[i].y, 0.f);
        }
        __syncthreads();

        float lg = b2s[k16];
        const float* hp = &shid[wid][ni][0];
        const float* wp = &W2t[k16][0];
#pragma unroll 8
        for (int j = 0; j < 128; j++) lg += hp[j] * wp[j];

        float m = lg;
        for (int msk = 1; msk < NK; msk <<= 1) m = fmaxf(m, __shfl_xor(m, msk, NK));
        float ex = expf(lg - m);
        float s = ex;
        for (int msk = 1; msk < NK; msk <<= 1) s += __shfl_xor(s, msk, NK);
        sout[(size_t)(d0 + ni) * NK + k16] = ex / s;
    }
}

// ---------------- launcher ----------------
extern "C" void kernel_launch(void* const* d_in, const int* in_sizes, int n_in,
                              void* d_out, int out_size, void* d_ws, size_t ws_size,
                              hipStream_t stream){
    const float* x      = (const float*)d_in[0];
    const int*   ei     = (const int*)d_in[1];
    const int*   srcv   = ei;
    const int*   dstv   = ei + NEDGES;
    const float* W1     = (const float*)d_in[2];
    const float* att_s1 = (const float*)d_in[3];
    const float* att_d1 = (const float*)d_in[4];
    const float* b1     = (const float*)d_in[5];
    const float* W2     = (const float*)d_in[6];
    const float* att_s2 = (const float*)d_in[7];
    const float* att_d2 = (const float*)d_in[8];
    const float* b2     = (const float*)d_in[9];
    const float* Wm1    = (const float*)d_in[10];
    const float* bm1    = (const float*)d_in[11];
    const float* Wm2    = (const float*)d_in[12];
    const float* bm2    = (const float*)d_in[13];

    float* out     = (float*)d_out;                     // s: [N,16]
    float* emb_out = out + (size_t)NNODES * NK;         // embeddings: [N,64]

    // workspace layout (all bf16 activations; 16B-aligned regions)
    u16* xb    = (u16*)d_ws;                            // N*128
    u16* h1b   = xb   + (size_t)NNODES * INC;           // N*256
    u16* hL1b  = h1b  + (size_t)NNODES * HC1;           // N*256
    u16* h2b   = hL1b + (size_t)NNODES * HC1;           // N*64
    u16* W1t   = h2b  + (size_t)NNODES * OUTC;          // 256*128
    u16* W2t   = W1t + 256 * 128;                       // 64*256
    float* as1 = (float*)(W2t + 64 * 256);              // N*8
    float* ad1 = as1 + (size_t)NNODES * NHEADS;         // N*8
    float* as2 = ad1 + (size_t)NNODES * NHEADS;         // N
    float* ad2 = as2 + NNODES;                          // N
    int* deg    = (int*)(ad2 + NNODES);                 // N
    int* rowptr = deg + NNODES;                         // N+1
    int* bsum   = rowptr + NNODES + 1;                  // 256
    int* boff   = bsum + 256;                           // 256
    int* fillc  = boff + 256;                           // N
    int* colv   = fillc + NNODES;                       // E

    hipMemsetAsync(deg, 0, NNODES * sizeof(int), stream);
    hipMemsetAsync(fillc, 0, NNODES * sizeof(int), stream);

    const int NB = (NNODES + 255) / 256;
    count_deg_k<<<(NEDGES + 255) / 256, 256, 0, stream>>>(dstv, deg);
    blocksum_k<<<NB, 256, 0, stream>>>(deg, bsum);
    scan_bsum_k<<<1, 256, 0, stream>>>(bsum, boff, NB);
    scan_write_k<<<NB, 256, 0, stream>>>(deg, boff, rowptr);
    fill_csr_k<<<(NEDGES + 255) / 256, 256, 0, stream>>>(srcv, dstv, rowptr, fillc, colv);

    // precision prep
    cast_x_k<<<(NNODES * INC) / 1024, 256, 0, stream>>>(x, xb);
    transpose_w1_k<<<128, 256, 0, stream>>>(W1, W1t);
    transpose_w2_k<<<64, 256, 0, stream>>>(W2, W2t);

    const int MT = (NNODES + 63) / 64;   // 782 m-tiles of 64 rows

    // layer 1: h1b = xb @ W1 (MFMA)
    gemm1_mfma_k<<<dim3(MT, HC1 / 16), 256, 0, stream>>>(xb, W1t, h1b);
    att1_k<<<NNODES / 4, 256, 0, stream>>>(h1b, att_s1, att_d1, as1, ad1);
    gat1_agg_k<<<NNODES / 4, 256, 0, stream>>>(h1b, as1, ad1, rowptr, colv, b1, hL1b);

    // layer 2: h2b = hL1b @ W2 (MFMA)
    gemm2_mfma_k<<<dim3(MT, OUTC / 16), 256, 0, stream>>>(hL1b, W2t, h2b);
    att2_k<<<NNODES / 4, 256, 0, stream>>>(h2b, att_s2, att_d2, as2, ad2);
    gat2_agg_k<<<NNODES / 4, 256, 0, stream>>>(h2b, as2, ad2, rowptr, colv, b2, emb_out);

    // MLP head + softmax
    mlp_k<<<512, 256, 0, stream>>>(emb_out, Wm1, bm1, Wm2, bm2, out);
}

// Round 6
// 354.222 us; speedup vs baseline: 1.1684x; 1.1684x over previous
//
#include <hip/hip_runtime.h>
#include <math.h>

#define NNODES 50000
#define NEDGES 400000
#define INC    128
#define HC1    256   // HEADS*HID
#define NHEADS 8
#define OUTC   64
#define NK     16
#define NEG_SLOPE 0.2f
#define EPS_F  1e-16f

typedef unsigned short u16;
typedef __attribute__((ext_vector_type(8))) short bf16x8;
typedef __attribute__((ext_vector_type(4))) float f32x4;

__device__ __forceinline__ float lrelu(float x){ return x > 0.f ? x : NEG_SLOPE * x; }
__device__ __forceinline__ float eluf(float x){ return x > 0.f ? x : (expf(x) - 1.f); }
__device__ __forceinline__ float bf2f(u16 v){ return __uint_as_float((unsigned)v << 16); }
__device__ __forceinline__ u16 f2bf(float f){
    unsigned u = __float_as_uint(f);
    unsigned r = (u + 0x7FFFu + ((u >> 16) & 1u)) >> 16;   // RTNE
    return (u16)r;
}
__device__ __forceinline__ short f2bf_s(float f){ return (short)f2bf(f); }

// ---------------- CSR build ----------------
__global__ void count_deg_k(const int* __restrict__ dst, int* __restrict__ deg){
    int e = blockIdx.x * 256 + threadIdx.x;
    if (e < NEDGES) atomicAdd(&deg[dst[e]], 1);
}

__global__ void blocksum_k(const int* __restrict__ deg, int* __restrict__ bsum){
    __shared__ int sm[4];
    int i = blockIdx.x * 256 + threadIdx.x;
    int v = (i < NNODES) ? deg[i] : 0;
    for (int off = 1; off < 64; off <<= 1) v += __shfl_xor(v, off);
    int lane = threadIdx.x & 63, wid = threadIdx.x >> 6;
    if (lane == 0) sm[wid] = v;
    __syncthreads();
    if (threadIdx.x == 0) bsum[blockIdx.x] = sm[0] + sm[1] + sm[2] + sm[3];
}

__global__ void scan_bsum_k(const int* __restrict__ bsum, int* __restrict__ boff, int nb){
    int tid = threadIdx.x;
    int v = (tid < nb) ? bsum[tid] : 0;
    int orig = v;
    int lane = tid & 63, wid = tid >> 6;
    for (int off = 1; off < 64; off <<= 1){ int t = __shfl_up(v, off); if (lane >= off) v += t; }
    __shared__ int wsum[4];
    if (lane == 63) wsum[wid] = v;
    __syncthreads();
    int add = 0;
    for (int w = 0; w < wid; w++) add += wsum[w];
    v += add;
    if (tid < nb) boff[tid] = v - orig;
}

__global__ void scan_write_k(const int* __restrict__ deg, const int* __restrict__ boff,
                             int* __restrict__ rowptr){
    int tid = threadIdx.x;
    int i = blockIdx.x * 256 + tid;
    int v = (i < NNODES) ? deg[i] : 0;
    int lane = tid & 63, wid = tid >> 6;
    int sv = v;
    for (int off = 1; off < 64; off <<= 1){ int t = __shfl_up(sv, off); if (lane >= off) sv += t; }
    __shared__ int wsum[4];
    if (lane == 63) wsum[wid] = sv;
    __syncthreads();
    int add = 0;
    for (int w = 0; w < wid; w++) add += wsum[w];
    sv += add;
    if (i < NNODES) rowptr[i + 1] = boff[blockIdx.x] + sv;
    if (i == 0) rowptr[0] = 0;
}

__global__ void fill_csr_k(const int* __restrict__ src, const int* __restrict__ dst,
                           const int* __restrict__ rowptr, int* __restrict__ fillc,
                           int* __restrict__ col){
    int e = blockIdx.x * 256 + threadIdx.x;
    if (e < NEDGES){
        int d = dst[e];
        int pos = atomicAdd(&fillc[d], 1);
        col[rowptr[d] + pos] = src[e];
    }
}

// ---------------- weight transposes (fp32 -> bf16, [N][K]) ----------------
__global__ void transpose_w1_k(const float* __restrict__ W, u16* __restrict__ Wt){
    int i = blockIdx.x * 256 + threadIdx.x;   // 32768
    int n = i >> 7, k = i & 127;
    Wt[i] = f2bf(W[k * 256 + n]);
}

__global__ void transpose_w2_k(const float* __restrict__ W, u16* __restrict__ Wt){
    int i = blockIdx.x * 256 + threadIdx.x;   // 16384
    int n = i >> 8, k = i & 255;
    Wt[i] = f2bf(W[k * 64 + n]);
}

// ---------------- L1: h1b[N,256] = bf16(x) @ W1, fused att1 ----------------
// block = 64 rows (4 waves x 16 rows); each wave computes all 256 cols (16 n-tiles).
__global__ void l1_k(const float* __restrict__ x, const u16* __restrict__ W1t,
                     const float* __restrict__ att_s, const float* __restrict__ att_d,
                     u16* __restrict__ h1b, float* __restrict__ as1, float* __restrict__ ad1){
    int lane = threadIdx.x & 63, wid = threadIdx.x >> 6;
    int ln = lane & 15, quad = lane >> 4;
    int m0 = blockIdx.x * 64 + wid * 16;
    int arow = m0 + ln; if (arow >= NNODES) arow = NNODES - 1;

    // A fragments: 4 k-tiles, cast fp32 -> bf16 in-register
    bf16x8 a[4];
#pragma unroll
    for (int kt = 0; kt < 4; kt++){
        const float* ap = x + (size_t)arow * INC + kt * 32 + quad * 8;
        float4 v0 = *(const float4*)ap;
        float4 v1 = *(const float4*)(ap + 4);
        bf16x8 t;
        t[0] = f2bf_s(v0.x); t[1] = f2bf_s(v0.y); t[2] = f2bf_s(v0.z); t[3] = f2bf_s(v0.w);
        t[4] = f2bf_s(v1.x); t[5] = f2bf_s(v1.y); t[6] = f2bf_s(v1.z); t[7] = f2bf_s(v1.w);
        a[kt] = t;
    }

    f32x4 acc[16];
#pragma unroll
    for (int nt = 0; nt < 16; nt++) acc[nt] = (f32x4){0.f, 0.f, 0.f, 0.f};

#pragma unroll
    for (int kt = 0; kt < 4; kt++){
#pragma unroll
        for (int nt = 0; nt < 16; nt++){
            bf16x8 b = *(const bf16x8*)(W1t + (size_t)(nt * 16 + ln) * INC + kt * 32 + quad * 8);
            acc[nt] = __builtin_amdgcn_mfma_f32_16x16x32_bf16(a[kt], b, acc[nt], 0, 0, 0);
        }
    }

    // write h1b
#pragma unroll
    for (int i = 0; i < 4; i++){
        int r = m0 + quad * 4 + i;
        if (r < NNODES){
#pragma unroll
            for (int nt = 0; nt < 16; nt++)
                h1b[(size_t)r * HC1 + nt * 16 + ln] = f2bf(acc[nt][i]);
        }
    }

    // fused att1: per row, per head h: dot over cols h*32..h*32+31 (nt = 2h, 2h+1)
#pragma unroll
    for (int i = 0; i < 4; i++){
        int r = m0 + quad * 4 + i;
        float ps_keep = 0.f, pd_keep = 0.f;
#pragma unroll
        for (int h = 0; h < 8; h++){
            float ps = acc[2 * h][i]     * att_s[h * 32 + ln]
                     + acc[2 * h + 1][i] * att_s[h * 32 + 16 + ln];
            float pd = acc[2 * h][i]     * att_d[h * 32 + ln]
                     + acc[2 * h + 1][i] * att_d[h * 32 + 16 + ln];
            ps += __shfl_xor(ps, 1); pd += __shfl_xor(pd, 1);
            ps += __shfl_xor(ps, 2); pd += __shfl_xor(pd, 2);
            ps += __shfl_xor(ps, 4); pd += __shfl_xor(pd, 4);
            ps += __shfl_xor(ps, 8); pd += __shfl_xor(pd, 8);
            if (ln == h){ ps_keep = ps; pd_keep = pd; }
        }
        if (ln < 8 && r < NNODES){
            as1[r * NHEADS + ln] = ps_keep;
            ad1[r * NHEADS + ln] = pd_keep;
        }
    }
}

// ---------------- L2: h2b[N,64] = hL1b @ W2, fused att2 ----------------
__global__ void l2_k(const u16* __restrict__ hL1b, const u16* __restrict__ W2t,
                     const float* __restrict__ att_s, const float* __restrict__ att_d,
                     u16* __restrict__ h2b, float* __restrict__ as2, float* __restrict__ ad2){
    int lane = threadIdx.x & 63, wid = threadIdx.x >> 6;
    int ln = lane & 15, quad = lane >> 4;
    int m0 = blockIdx.x * 64 + wid * 16;
    int arow = m0 + ln; if (arow >= NNODES) arow = NNODES - 1;

    f32x4 acc[4];
#pragma unroll
    for (int nt = 0; nt < 4; nt++) acc[nt] = (f32x4){0.f, 0.f, 0.f, 0.f};

#pragma unroll
    for (int kt = 0; kt < 8; kt++){
        bf16x8 a = *(const bf16x8*)(hL1b + (size_t)arow * HC1 + kt * 32 + quad * 8);
#pragma unroll
        for (int nt = 0; nt < 4; nt++){
            bf16x8 b = *(const bf16x8*)(W2t + (size_t)(nt * 16 + ln) * HC1 + kt * 32 + quad * 8);
            acc[nt] = __builtin_amdgcn_mfma_f32_16x16x32_bf16(a, b, acc[nt], 0, 0, 0);
        }
    }

#pragma unroll
    for (int i = 0; i < 4; i++){
        int r = m0 + quad * 4 + i;
        if (r < NNODES){
#pragma unroll
            for (int nt = 0; nt < 4; nt++)
                h2b[(size_t)r * OUTC + nt * 16 + ln] = f2bf(acc[nt][i]);
        }
        // fused att2 (1 head over 64 cols)
        float ps = acc[0][i] * att_s[ln]      + acc[1][i] * att_s[16 + ln]
                 + acc[2][i] * att_s[32 + ln] + acc[3][i] * att_s[48 + ln];
        float pd = acc[0][i] * att_d[ln]      + acc[1][i] * att_d[16 + ln]
                 + acc[2][i] * att_d[32 + ln] + acc[3][i] * att_d[48 + ln];
        ps += __shfl_xor(ps, 1); pd += __shfl_xor(pd, 1);
        ps += __shfl_xor(ps, 2); pd += __shfl_xor(pd, 2);
        ps += __shfl_xor(ps, 4); pd += __shfl_xor(pd, 4);
        ps += __shfl_xor(ps, 8); pd += __shfl_xor(pd, 8);
        if (ln == 0 && r < NNODES){ as2[r] = ps; ad2[r] = pd; }
    }
}

// ---------------- GAT layer 1 aggregation (R3 phases 1-2; chunked-alpha phase 3) ----------------
__global__ void gat1_agg_k(const u16* __restrict__ h1b, const float* __restrict__ as1,
                           const float* __restrict__ ad1, const int* __restrict__ rowptr,
                           const int* __restrict__ col, const float* __restrict__ b1,
                           u16* __restrict__ outb){
    int lane = threadIdx.x & 63, wid = threadIdx.x >> 6;
    int d = blockIdx.x * 4 + wid;
    int row0 = rowptr[d];
    int deg  = rowptr[d + 1] - row0;

    // phase 1/2 layout: lane = j*8 + h8
    int h8 = lane & 7, j = lane >> 3;
    float adst      = ad1[d * NHEADS + h8];
    float asrc_self = as1[d * NHEADS + h8];
    float e_self = lrelu(asrc_self + adst);

    float vmax = e_self;
    for (int base = 0; base < deg; base += 8){
        int idx = base + j;
        if (idx < deg){
            int s = col[row0 + idx];
            vmax = fmaxf(vmax, lrelu(as1[s * NHEADS + h8] + adst));
        }
    }
    vmax = fmaxf(vmax, __shfl_xor(vmax, 8));
    vmax = fmaxf(vmax, __shfl_xor(vmax, 16));
    vmax = fmaxf(vmax, __shfl_xor(vmax, 32));

    float vsum = (j == 0) ? expf(e_self - vmax) : 0.f;
    for (int base = 0; base < deg; base += 8){
        int idx = base + j;
        if (idx < deg){
            int s = col[row0 + idx];
            vsum += expf(lrelu(as1[s * NHEADS + h8] + adst) - vmax);
        }
    }
    vsum += __shfl_xor(vsum, 8);
    vsum += __shfl_xor(vsum, 16);
    vsum += __shfl_xor(vsum, 32);
    float rden = 1.f / (vsum + EPS_F);
    // after reductions: each lane holds vmax/rden for ITS h8

    // phase 3: lane covers channels 4*lane..4*lane+3, head hc = lane>>3
    int hc = lane >> 3;
    int cbase = lane * 4;

    float a_self = __shfl(expf(e_self - vmax) * rden, hc);   // lane hc: (j=0, h8=hc)
    ushort4 us = *(const ushort4*)(h1b + (size_t)d * HC1 + cbase);
    float4 acc = make_float4(a_self * bf2f(us.x), a_self * bf2f(us.y),
                             a_self * bf2f(us.z), a_self * bf2f(us.w));

    for (int base = 0; base < deg; base += 8){
        int eidx = base + j;
        int cj = (eidx < deg) ? col[row0 + eidx] : d;         // lanes j*8..j*8+7 share addr
        float ae = (eidx < deg)
                 ? expf(lrelu(as1[cj * NHEADS + h8] + adst) - vmax) * rden : 0.f;
        int nloc = min(8, deg - base);
        for (int t = 0; t < nloc; t++){
            int s   = __shfl(cj, t * 8);                      // uniform idx
            float a = __shfl(ae, t * 8 + hc);                 // alpha(edge t, head hc)
            ushort4 u4 = *(const ushort4*)(h1b + (size_t)s * HC1 + cbase);
            acc.x += a * bf2f(u4.x); acc.y += a * bf2f(u4.y);
            acc.z += a * bf2f(u4.z); acc.w += a * bf2f(u4.w);
        }
    }
    float4 bb = *(const float4*)(b1 + cbase);
    ushort4 ob = make_ushort4(f2bf(eluf(acc.x + bb.x)), f2bf(eluf(acc.y + bb.y)),
                              f2bf(eluf(acc.z + bb.z)), f2bf(eluf(acc.w + bb.w)));
    *(ushort4*)(outb + (size_t)d * HC1 + cbase) = ob;
}

// ---------------- GAT layer 2 aggregation (alpha once, shfl broadcast) ----------------
__global__ void gat2_agg_k(const u16* __restrict__ h2b, const float* __restrict__ as2,
                           const float* __restrict__ ad2, const int* __restrict__ rowptr,
                           const int* __restrict__ col, const float* __restrict__ b2,
                           float* __restrict__ emb){
    int lane = threadIdx.x & 63, wid = threadIdx.x >> 6;
    int d = blockIdx.x * 4 + wid;
    int row0 = rowptr[d];
    int deg  = rowptr[d + 1] - row0;

    float adst = ad2[d];
    float e_self = lrelu(as2[d] + adst);

    if (deg <= 64){
        int sv = (lane < deg) ? col[row0 + lane] : d;
        float e_lane = (lane < deg) ? lrelu(as2[sv] + adst) : -3e38f;
        float vmax = fmaxf(e_self, e_lane);
        for (int m = 1; m < 64; m <<= 1) vmax = fmaxf(vmax, __shfl_xor(vmax, m));
        float exl = (lane < deg) ? expf(e_lane - vmax) : 0.f;
        float vsum = exl + ((lane == 0) ? expf(e_self - vmax) : 0.f);
        for (int m = 1; m < 64; m <<= 1) vsum += __shfl_xor(vsum, m);
        float rden = 1.f / (vsum + EPS_F);
        float alpha_l = exl * rden;

        float acc = expf(e_self - vmax) * rden * bf2f(h2b[(size_t)d * OUTC + lane]);
        for (int t = 0; t < deg; t++){
            int s   = __shfl(sv, t);
            float a = __shfl(alpha_l, t);
            acc += a * bf2f(h2b[(size_t)s * OUTC + lane]);
        }
        emb[(size_t)d * OUTC + lane] = acc + b2[lane];
    } else {
        float vmax = e_self;
        for (int base = 0; base < deg; base += 64){
            int idx = base + lane;
            if (idx < deg){
                int s = col[row0 + idx];
                vmax = fmaxf(vmax, lrelu(as2[s] + adst));
            }
        }
        for (int m = 1; m < 64; m <<= 1) vmax = fmaxf(vmax, __shfl_xor(vmax, m));
        float vsum = (lane == 0) ? expf(e_self - vmax) : 0.f;
        for (int base = 0; base < deg; base += 64){
            int idx = base + lane;
            if (idx < deg){
                int s = col[row0 + idx];
                vsum += expf(lrelu(as2[s] + adst) - vmax);
            }
        }
        for (int m = 1; m < 64; m <<= 1) vsum += __shfl_xor(vsum, m);
        float rden = 1.f / (vsum + EPS_F);
        float alpha = expf(e_self - vmax) * rden;
        float acc = alpha * bf2f(h2b[(size_t)d * OUTC + lane]);
        for (int idx = 0; idx < deg; idx++){
            int s = col[row0 + idx];
            float a = expf(lrelu(as2[s] + adst) - vmax) * rden;
            acc += a * bf2f(h2b[(size_t)s * OUTC + lane]);
        }
        emb[(size_t)d * OUTC + lane] = acc + b2[lane];
    }
}

// ---------------- MLP head + softmax: LDS-resident weights, 4 nodes/wave ----------------
__global__ __launch_bounds__(256, 2) void mlp_k(const float* __restrict__ emb,
                      const float* __restrict__ Wm1, const float* __restrict__ bm1,
                      const float* __restrict__ Wm2, const float* __restrict__ bm2,
                      float* __restrict__ sout){
    __shared__ float W1a[64][64];
    __shared__ float W1b[64][64];
    __shared__ float W2t[16][132];
    __shared__ float b1s[128];
    __shared__ float b2s[16];
    __shared__ float semb[4][64][4];
    __shared__ float shid[4][4][132];

    int tx = threadIdx.x;
    for (int i = tx; i < 64 * 64; i += 256){
        int c = i >> 6, l = i & 63;
        W1a[c][l] = Wm1[c * 128 + l];
        W1b[c][l] = Wm1[c * 128 + 64 + l];
    }
    for (int i = tx; i < 16 * 128; i += 256){
        int k = i >> 7, j = i & 127;
        W2t[k][j] = Wm2[j * NK + k];
    }
    if (tx < 128) b1s[tx] = bm1[tx];
    if (tx < 16)  b2s[tx] = bm2[tx];
    __syncthreads();

    int lane = tx & 63, wid = tx >> 6;
    int k16 = lane & 15, ni = lane >> 4;

    for (int base = blockIdx.x * 16; base < NNODES; base += gridDim.x * 16){
        int d0 = base + wid * 4;
#pragma unroll
        for (int i = 0; i < 4; i++)
            semb[wid][lane][i] = emb[(size_t)(d0 + i) * OUTC + lane];
        __syncthreads();

        float2 acc[4];
#pragma unroll
        for (int i = 0; i < 4; i++) acc[i] = make_float2(b1s[lane], b1s[64 + lane]);
#pragma unroll 8
        for (int c = 0; c < 64; c++){
            float wa = W1a[c][lane];
            float wb = W1b[c][lane];
            float4 e = *(const float4*)&semb[wid][c][0];
            acc[0].x += e.x * wa; acc[0].y += e.x * wb;
            acc[1].x += e.y * wa; acc[1].y += e.y * wb;
            acc[2].x += e.z * wa; acc[2].y += e.z * wb;
            acc[3].x += e.w * wa; acc[3].y += e.w * wb;
        }
#pragma unroll
        for (int i = 0; i < 4; i++){
            shid[wid][i][lane]      = fmaxf(acc[i].x, 0.f);
            shid[wid][i][64 + lane] = fmaxf(acc[i].y, 0.f);
        }
        __syncthreads();

        float lg = b2s[k16];
        const float* hp = &shid[wid][ni][0];
        const float* wp = &W2t[k16][0];
#pragma unroll 8
        for (int j = 0; j < 128; j++) lg += hp[j] * wp[j];

        float m = lg;
        for (int msk = 1; msk < NK; msk <<= 1) m = fmaxf(m, __shfl_xor(m, msk, NK));
        float ex = expf(lg - m);
        float s = ex;
        for (int msk = 1; msk < NK; msk <<= 1) s += __shfl_xor(s, msk, NK);
        sout[(size_t)(d0 + ni) * NK + k16] = ex / s;
    }
}

// ---------------- launcher ----------------
extern "C" void kernel_launch(void* const* d_in, const int* in_sizes, int n_in,
                              void* d_out, int out_size, void* d_ws, size_t ws_size,
                              hipStream_t stream){
    const float* x      = (const float*)d_in[0];
    const int*   ei     = (const int*)d_in[1];
    const int*   srcv   = ei;
    const int*   dstv   = ei + NEDGES;
    const float* W1     = (const float*)d_in[2];
    const float* att_s1 = (const float*)d_in[3];
    const float* att_d1 = (const float*)d_in[4];
    const float* b1     = (const float*)d_in[5];
    const float* W2     = (const float*)d_in[6];
    const float* att_s2 = (const float*)d_in[7];
    const float* att_d2 = (const float*)d_in[8];
    const float* b2     = (const float*)d_in[9];
    const float* Wm1    = (const float*)d_in[10];
    const float* bm1    = (const float*)d_in[11];
    const float* Wm2    = (const float*)d_in[12];
    const float* bm2    = (const float*)d_in[13];

    float* out     = (float*)d_out;                     // s: [N,16]
    float* emb_out = out + (size_t)NNODES * NK;         // embeddings: [N,64]

    // workspace layout
    u16* h1b   = (u16*)d_ws;                            // N*256
    u16* hL1b  = h1b  + (size_t)NNODES * HC1;           // N*256
    u16* h2b   = hL1b + (size_t)NNODES * HC1;           // N*64
    u16* W1t   = h2b  + (size_t)NNODES * OUTC;          // 256*128
    u16* W2t   = W1t + 256 * 128;                       // 64*256
    float* as1 = (float*)(W2t + 64 * 256);              // N*8
    float* ad1 = as1 + (size_t)NNODES * NHEADS;         // N*8
    float* as2 = ad1 + (size_t)NNODES * NHEADS;         // N
    float* ad2 = as2 + NNODES;                          // N
    int* deg    = (int*)(ad2 + NNODES);                 // N
    int* rowptr = deg + NNODES;                         // N+1
    int* bsum   = rowptr + NNODES + 1;                  // 256
    int* boff   = bsum + 256;                           // 256
    int* fillc  = boff + 256;                           // N
    int* colv   = fillc + NNODES;                       // E

    hipMemsetAsync(deg, 0, NNODES * sizeof(int), stream);
    hipMemsetAsync(fillc, 0, NNODES * sizeof(int), stream);

    const int NB = (NNODES + 255) / 256;
    count_deg_k<<<(NEDGES + 255) / 256, 256, 0, stream>>>(dstv, deg);
    blocksum_k<<<NB, 256, 0, stream>>>(deg, bsum);
    scan_bsum_k<<<1, 256, 0, stream>>>(bsum, boff, NB);
    scan_write_k<<<NB, 256, 0, stream>>>(deg, boff, rowptr);
    fill_csr_k<<<(NEDGES + 255) / 256, 256, 0, stream>>>(srcv, dstv, rowptr, fillc, colv);

    transpose_w1_k<<<128, 256, 0, stream>>>(W1, W1t);
    transpose_w2_k<<<64, 256, 0, stream>>>(W2, W2t);

    const int MB = (NNODES + 63) / 64;   // 782

    // layer 1 (gemm + att fused) then aggregation
    l1_k<<<MB, 256, 0, stream>>>(x, W1t, att_s1, att_d1, h1b, as1, ad1);
    gat1_agg_k<<<NNODES / 4, 256, 0, stream>>>(h1b, as1, ad1, rowptr, colv, b1, hL1b);

    // layer 2 (gemm + att fused) then aggregation
    l2_k<<<MB, 256, 0, stream>>>(hL1b, W2t, att_s2, att_d2, h2b, as2, ad2);
    gat2_agg_k<<<NNODES / 4, 256, 0, stream>>>(h2b, as2, ad2, rowptr, colv, b2, emb_out);

    // MLP head + softmax
    mlp_k<<<512, 256, 0, stream>>>(emb_out, Wm1, bm1, Wm2, bm2, out);
}

// Round 7
// 329.209 us; speedup vs baseline: 1.2571x; 1.0760x over previous
//
#include <hip/hip_runtime.h>
#include <math.h>

#define NNODES 50000
#define NEDGES 400000
#define INC    128
#define HC1    256   // HEADS*HID
#define NHEADS 8
#define OUTC   64
#define NK     16
#define NEG_SLOPE 0.2f
#define EPS_F  1e-16f

typedef unsigned short u16;
typedef __attribute__((ext_vector_type(8))) short bf16x8;
typedef __attribute__((ext_vector_type(4))) float f32x4;

__device__ __forceinline__ float lrelu(float x){ return x > 0.f ? x : NEG_SLOPE * x; }
__device__ __forceinline__ float eluf(float x){ return x > 0.f ? x : (expf(x) - 1.f); }
__device__ __forceinline__ float bf2f(u16 v){ return __uint_as_float((unsigned)v << 16); }
__device__ __forceinline__ u16 f2bf(float f){
    unsigned u = __float_as_uint(f);
    unsigned r = (u + 0x7FFFu + ((u >> 16) & 1u)) >> 16;   // RTNE
    return (u16)r;
}
__device__ __forceinline__ short f2bf_s(float f){ return (short)f2bf(f); }

// ---------------- CSR build ----------------
__global__ void count_deg_k(const int* __restrict__ dst, int* __restrict__ deg){
    int e = blockIdx.x * 256 + threadIdx.x;
    if (e < NEDGES) atomicAdd(&deg[dst[e]], 1);
}

__global__ void blocksum_k(const int* __restrict__ deg, int* __restrict__ bsum){
    __shared__ int sm[4];
    int i = blockIdx.x * 256 + threadIdx.x;
    int v = (i < NNODES) ? deg[i] : 0;
    for (int off = 1; off < 64; off <<= 1) v += __shfl_xor(v, off);
    int lane = threadIdx.x & 63, wid = threadIdx.x >> 6;
    if (lane == 0) sm[wid] = v;
    __syncthreads();
    if (threadIdx.x == 0) bsum[blockIdx.x] = sm[0] + sm[1] + sm[2] + sm[3];
}

__global__ void scan_bsum_k(const int* __restrict__ bsum, int* __restrict__ boff, int nb){
    int tid = threadIdx.x;
    int v = (tid < nb) ? bsum[tid] : 0;
    int orig = v;
    int lane = tid & 63, wid = tid >> 6;
    for (int off = 1; off < 64; off <<= 1){ int t = __shfl_up(v, off); if (lane >= off) v += t; }
    __shared__ int wsum[4];
    if (lane == 63) wsum[wid] = v;
    __syncthreads();
    int add = 0;
    for (int w = 0; w < wid; w++) add += wsum[w];
    v += add;
    if (tid < nb) boff[tid] = v - orig;
}

__global__ void scan_write_k(const int* __restrict__ deg, const int* __restrict__ boff,
                             int* __restrict__ rowptr){
    int tid = threadIdx.x;
    int i = blockIdx.x * 256 + tid;
    int v = (i < NNODES) ? deg[i] : 0;
    int lane = tid & 63, wid = tid >> 6;
    int sv = v;
    for (int off = 1; off < 64; off <<= 1){ int t = __shfl_up(sv, off); if (lane >= off) sv += t; }
    __shared__ int wsum[4];
    if (lane == 63) wsum[wid] = sv;
    __syncthreads();
    int add = 0;
    for (int w = 0; w < wid; w++) add += wsum[w];
    sv += add;
    if (i < NNODES) rowptr[i + 1] = boff[blockIdx.x] + sv;
    if (i == 0) rowptr[0] = 0;
}

__global__ void fill_csr_k(const int* __restrict__ src, const int* __restrict__ dst,
                           const int* __restrict__ rowptr, int* __restrict__ fillc,
                           int* __restrict__ col){
    int e = blockIdx.x * 256 + threadIdx.x;
    if (e < NEDGES){
        int d = dst[e];
        int pos = atomicAdd(&fillc[d], 1);
        col[rowptr[d] + pos] = src[e];
    }
}

// ---------------- weight transposes (fp32 -> bf16, [N][K]) ----------------
__global__ void transpose_w1_k(const float* __restrict__ W, u16* __restrict__ Wt){
    int i = blockIdx.x * 256 + threadIdx.x;   // 32768
    int n = i >> 7, k = i & 127;
    Wt[i] = f2bf(W[k * 256 + n]);
}

__global__ void transpose_w2_k(const float* __restrict__ W, u16* __restrict__ Wt){
    int i = blockIdx.x * 256 + threadIdx.x;   // 16384
    int n = i >> 8, k = i & 255;
    Wt[i] = f2bf(W[k * 64 + n]);
}

// ---------------- L1: h1b[N,256] = bf16(x) @ W1, fused att1 ----------------
__global__ void l1_k(const float* __restrict__ x, const u16* __restrict__ W1t,
                     const float* __restrict__ att_s, const float* __restrict__ att_d,
                     u16* __restrict__ h1b, float* __restrict__ as1, float* __restrict__ ad1){
    int lane = threadIdx.x & 63, wid = threadIdx.x >> 6;
    int ln = lane & 15, quad = lane >> 4;
    int m0 = blockIdx.x * 64 + wid * 16;
    int arow = m0 + ln; if (arow >= NNODES) arow = NNODES - 1;

    bf16x8 a[4];
#pragma unroll
    for (int kt = 0; kt < 4; kt++){
        const float* ap = x + (size_t)arow * INC + kt * 32 + quad * 8;
        float4 v0 = *(const float4*)ap;
        float4 v1 = *(const float4*)(ap + 4);
        bf16x8 t;
        t[0] = f2bf_s(v0.x); t[1] = f2bf_s(v0.y); t[2] = f2bf_s(v0.z); t[3] = f2bf_s(v0.w);
        t[4] = f2bf_s(v1.x); t[5] = f2bf_s(v1.y); t[6] = f2bf_s(v1.z); t[7] = f2bf_s(v1.w);
        a[kt] = t;
    }

    f32x4 acc[16];
#pragma unroll
    for (int nt = 0; nt < 16; nt++) acc[nt] = (f32x4){0.f, 0.f, 0.f, 0.f};

#pragma unroll
    for (int kt = 0; kt < 4; kt++){
#pragma unroll
        for (int nt = 0; nt < 16; nt++){
            bf16x8 b = *(const bf16x8*)(W1t + (size_t)(nt * 16 + ln) * INC + kt * 32 + quad * 8);
            acc[nt] = __builtin_amdgcn_mfma_f32_16x16x32_bf16(a[kt], b, acc[nt], 0, 0, 0);
        }
    }

#pragma unroll
    for (int i = 0; i < 4; i++){
        int r = m0 + quad * 4 + i;
        if (r < NNODES){
#pragma unroll
            for (int nt = 0; nt < 16; nt++)
                h1b[(size_t)r * HC1 + nt * 16 + ln] = f2bf(acc[nt][i]);
        }
    }

#pragma unroll
    for (int i = 0; i < 4; i++){
        int r = m0 + quad * 4 + i;
        float ps_keep = 0.f, pd_keep = 0.f;
#pragma unroll
        for (int h = 0; h < 8; h++){
            float ps = acc[2 * h][i]     * att_s[h * 32 + ln]
                     + acc[2 * h + 1][i] * att_s[h * 32 + 16 + ln];
            float pd = acc[2 * h][i]     * att_d[h * 32 + ln]
                     + acc[2 * h + 1][i] * att_d[h * 32 + 16 + ln];
            ps += __shfl_xor(ps, 1); pd += __shfl_xor(pd, 1);
            ps += __shfl_xor(ps, 2); pd += __shfl_xor(pd, 2);
            ps += __shfl_xor(ps, 4); pd += __shfl_xor(pd, 4);
            ps += __shfl_xor(ps, 8); pd += __shfl_xor(pd, 8);
            if (ln == h){ ps_keep = ps; pd_keep = pd; }
        }
        if (ln < 8 && r < NNODES){
            as1[r * NHEADS + ln] = ps_keep;
            ad1[r * NHEADS + ln] = pd_keep;
        }
    }
}

// ---------------- L2: h2b[N,64] = hL1b @ W2, fused att2 ----------------
__global__ void l2_k(const u16* __restrict__ hL1b, const u16* __restrict__ W2t,
                     const float* __restrict__ att_s, const float* __restrict__ att_d,
                     u16* __restrict__ h2b, float* __restrict__ as2, float* __restrict__ ad2){
    int lane = threadIdx.x & 63, wid = threadIdx.x >> 6;
    int ln = lane & 15, quad = lane >> 4;
    int m0 = blockIdx.x * 64 + wid * 16;
    int arow = m0 + ln; if (arow >= NNODES) arow = NNODES - 1;

    f32x4 acc[4];
#pragma unroll
    for (int nt = 0; nt < 4; nt++) acc[nt] = (f32x4){0.f, 0.f, 0.f, 0.f};

#pragma unroll
    for (int kt = 0; kt < 8; kt++){
        bf16x8 a = *(const bf16x8*)(hL1b + (size_t)arow * HC1 + kt * 32 + quad * 8);
#pragma unroll
        for (int nt = 0; nt < 4; nt++){
            bf16x8 b = *(const bf16x8*)(W2t + (size_t)(nt * 16 + ln) * HC1 + kt * 32 + quad * 8);
            acc[nt] = __builtin_amdgcn_mfma_f32_16x16x32_bf16(a, b, acc[nt], 0, 0, 0);
        }
    }

#pragma unroll
    for (int i = 0; i < 4; i++){
        int r = m0 + quad * 4 + i;
        if (r < NNODES){
#pragma unroll
            for (int nt = 0; nt < 4; nt++)
                h2b[(size_t)r * OUTC + nt * 16 + ln] = f2bf(acc[nt][i]);
        }
        float ps = acc[0][i] * att_s[ln]      + acc[1][i] * att_s[16 + ln]
                 + acc[2][i] * att_s[32 + ln] + acc[3][i] * att_s[48 + ln];
        float pd = acc[0][i] * att_d[ln]      + acc[1][i] * att_d[16 + ln]
                 + acc[2][i] * att_d[32 + ln] + acc[3][i] * att_d[48 + ln];
        ps += __shfl_xor(ps, 1); pd += __shfl_xor(pd, 1);
        ps += __shfl_xor(ps, 2); pd += __shfl_xor(pd, 2);
        ps += __shfl_xor(ps, 4); pd += __shfl_xor(pd, 4);
        ps += __shfl_xor(ps, 8); pd += __shfl_xor(pd, 8);
        if (ln == 0 && r < NNODES){ as2[r] = ps; ad2[r] = pd; }
    }
}

// ---------------- GAT layer 1 aggregation v3 ----------------
// phases 1-2 as R6 (known-good); phase 3: half-wave per edge, fixed unrolled 8 gathers/chunk
__global__ void gat1_agg_k(const u16* __restrict__ h1b, const float* __restrict__ as1,
                           const float* __restrict__ ad1, const int* __restrict__ rowptr,
                           const int* __restrict__ col, const float* __restrict__ b1,
                           u16* __restrict__ outb){
    int lane = threadIdx.x & 63, wid = threadIdx.x >> 6;
    int d = blockIdx.x * 4 + wid;
    int row0 = rowptr[d];
    int deg  = rowptr[d + 1] - row0;

    // phase 1/2 layout: lane = j*8 + h8
    int h8 = lane & 7, j = lane >> 3;
    float adst      = ad1[d * NHEADS + h8];
    float asrc_self = as1[d * NHEADS + h8];
    float e_self = lrelu(asrc_self + adst);

    float vmax = e_self;
    for (int base = 0; base < deg; base += 8){
        int idx = base + j;
        if (idx < deg){
            int s = col[row0 + idx];
            vmax = fmaxf(vmax, lrelu(as1[s * NHEADS + h8] + adst));
        }
    }
    vmax = fmaxf(vmax, __shfl_xor(vmax, 8));
    vmax = fmaxf(vmax, __shfl_xor(vmax, 16));
    vmax = fmaxf(vmax, __shfl_xor(vmax, 32));

    float vsum = (j == 0) ? expf(e_self - vmax) : 0.f;
    for (int base = 0; base < deg; base += 8){
        int idx = base + j;
        if (idx < deg){
            int s = col[row0 + idx];
            vsum += expf(lrelu(as1[s * NHEADS + h8] + adst) - vmax);
        }
    }
    vsum += __shfl_xor(vsum, 8);
    vsum += __shfl_xor(vsum, 16);
    vsum += __shfl_xor(vsum, 32);
    float rden = 1.f / (vsum + EPS_F);
    // lane L holds vmax/rden for head L&7

    // phase 3: half-wave per edge; lane covers channels l32*8..l32*8+7 (head hd = l32>>2)
    int hw = lane >> 5, l32 = lane & 31, hd = l32 >> 2;
    float sa_reg = expf(e_self - vmax) * rden;        // self alpha for head h8 (valid lanes 0..7)
    float sa_b   = __shfl(sa_reg, hd);
    float asf    = hw ? 0.f : sa_b;                   // half 0 adds self

    float acc[8];
    {
        uint4 w = *(const uint4*)(h1b + (size_t)d * HC1 + l32 * 8);
        acc[0] = asf * __uint_as_float(w.x << 16);
        acc[1] = asf * __uint_as_float(w.x & 0xFFFF0000u);
        acc[2] = asf * __uint_as_float(w.y << 16);
        acc[3] = asf * __uint_as_float(w.y & 0xFFFF0000u);
        acc[4] = asf * __uint_as_float(w.z << 16);
        acc[5] = asf * __uint_as_float(w.z & 0xFFFF0000u);
        acc[6] = asf * __uint_as_float(w.w << 16);
        acc[7] = asf * __uint_as_float(w.w & 0xFFFF0000u);
    }

    for (int base = 0; base < deg; base += 8){
        int eidx = base + j;
        int cj = (eidx < deg) ? col[row0 + eidx] : d;
        float ae = (eidx < deg)
                 ? expf(lrelu(as1[cj * NHEADS + h8] + adst) - vmax) * rden : 0.f;
#pragma unroll
        for (int st = 0; st < 4; st++){
            int it = st * 2 + hw;                    // edge slot 0..7 in chunk
            int s  = __shfl(cj, it * 8);
            float a = __shfl(ae, it * 8 + hd);
            uint4 w = *(const uint4*)(h1b + (size_t)s * HC1 + l32 * 8);
            acc[0] += a * __uint_as_float(w.x << 16);
            acc[1] += a * __uint_as_float(w.x & 0xFFFF0000u);
            acc[2] += a * __uint_as_float(w.y << 16);
            acc[3] += a * __uint_as_float(w.y & 0xFFFF0000u);
            acc[4] += a * __uint_as_float(w.z << 16);
            acc[5] += a * __uint_as_float(w.z & 0xFFFF0000u);
            acc[6] += a * __uint_as_float(w.w << 16);
            acc[7] += a * __uint_as_float(w.w & 0xFFFF0000u);
        }
    }
#pragma unroll
    for (int k = 0; k < 8; k++) acc[k] += __shfl_xor(acc[k], 32);

    if (lane < 32){
        float4 b0 = *(const float4*)(b1 + l32 * 8);
        float4 b4 = *(const float4*)(b1 + l32 * 8 + 4);
        uint4 o;
        o.x = (unsigned)f2bf(eluf(acc[0] + b0.x)) | ((unsigned)f2bf(eluf(acc[1] + b0.y)) << 16);
        o.y = (unsigned)f2bf(eluf(acc[2] + b0.z)) | ((unsigned)f2bf(eluf(acc[3] + b0.w)) << 16);
        o.z = (unsigned)f2bf(eluf(acc[4] + b4.x)) | ((unsigned)f2bf(eluf(acc[5] + b4.y)) << 16);
        o.w = (unsigned)f2bf(eluf(acc[6] + b4.z)) | ((unsigned)f2bf(eluf(acc[7] + b4.w)) << 16);
        *(uint4*)(outb + (size_t)d * HC1 + l32 * 8) = o;
    }
}

// ---------------- GAT layer 2 aggregation v3 (quarter-wave per edge) ----------------
__global__ void gat2_agg_k(const u16* __restrict__ h2b, const float* __restrict__ as2,
                           const float* __restrict__ ad2, const int* __restrict__ rowptr,
                           const int* __restrict__ col, const float* __restrict__ b2,
                           float* __restrict__ emb){
    int lane = threadIdx.x & 63, wid = threadIdx.x >> 6;
    int d = blockIdx.x * 4 + wid;
    int row0 = rowptr[d];
    int deg  = rowptr[d + 1] - row0;

    float adst = ad2[d];
    float e_self = lrelu(as2[d] + adst);

    if (deg <= 64){
        int sv = (lane < deg) ? col[row0 + lane] : d;
        float e_lane = (lane < deg) ? lrelu(as2[sv] + adst) : -3e38f;
        float vmax = fmaxf(e_self, e_lane);
        for (int m = 1; m < 64; m <<= 1) vmax = fmaxf(vmax, __shfl_xor(vmax, m));
        float exl = (lane < deg) ? expf(e_lane - vmax) : 0.f;
        float vsum = exl + ((lane == 0) ? expf(e_self - vmax) : 0.f);
        for (int m = 1; m < 64; m <<= 1) vsum += __shfl_xor(vsum, m);
        float rden = 1.f / (vsum + EPS_F);
        float alpha_l = exl * rden;               // 0 for lanes >= deg
        float sa = expf(e_self - vmax) * rden;

        int q = lane >> 4, c4 = (lane & 15) * 4;
        float a0 = (q == 0) ? sa : 0.f;
        float4 acc;
        {
            ushort4 u = *(const ushort4*)(h2b + (size_t)d * OUTC + c4);
            acc = make_float4(a0 * bf2f(u.x), a0 * bf2f(u.y), a0 * bf2f(u.z), a0 * bf2f(u.w));
        }
        for (int it0 = 0; it0 < deg; it0 += 8){
#pragma unroll
            for (int k = 0; k < 2; k++){
                int it = it0 + k * 4 + q;
                int itc = min(it, 63);
                int s   = __shfl(sv, itc);
                float a = __shfl(alpha_l, itc);
                ushort4 u = *(const ushort4*)(h2b + (size_t)s * OUTC + c4);
                acc.x += a * bf2f(u.x); acc.y += a * bf2f(u.y);
                acc.z += a * bf2f(u.z); acc.w += a * bf2f(u.w);
            }
        }
        acc.x += __shfl_xor(acc.x, 16); acc.y += __shfl_xor(acc.y, 16);
        acc.z += __shfl_xor(acc.z, 16); acc.w += __shfl_xor(acc.w, 16);
        acc.x += __shfl_xor(acc.x, 32); acc.y += __shfl_xor(acc.y, 32);
        acc.z += __shfl_xor(acc.z, 32); acc.w += __shfl_xor(acc.w, 32);
        if (lane < 16){
            float4 bb = *(const float4*)(b2 + c4);
            float4 o = make_float4(acc.x + bb.x, acc.y + bb.y, acc.z + bb.z, acc.w + bb.w);
            *(float4*)(emb + (size_t)d * OUTC + c4) = o;
        }
    } else {
        float vmax = e_self;
        for (int base = 0; base < deg; base += 64){
            int idx = base + lane;
            if (idx < deg){
                int s = col[row0 + idx];
                vmax = fmaxf(vmax, lrelu(as2[s] + adst));
            }
        }
        for (int m = 1; m < 64; m <<= 1) vmax = fmaxf(vmax, __shfl_xor(vmax, m));
        float vsum = (lane == 0) ? expf(e_self - vmax) : 0.f;
        for (int base = 0; base < deg; base += 64){
            int idx = base + lane;
            if (idx < deg){
                int s = col[row0 + idx];
                vsum += expf(lrelu(as2[s] + adst) - vmax);
            }
        }
        for (int m = 1; m < 64; m <<= 1) vsum += __shfl_xor(vsum, m);
        float rden = 1.f / (vsum + EPS_F);
        float alpha = expf(e_self - vmax) * rden;
        float acc = alpha * bf2f(h2b[(size_t)d * OUTC + lane]);
        for (int idx = 0; idx < deg; idx++){
            int s = col[row0 + idx];
            float a = expf(lrelu(as2[s] + adst) - vmax) * rden;
            acc += a * bf2f(h2b[(size_t)s * OUTC + lane]);
        }
        emb[(size_t)d * OUTC + lane] = acc + b2[lane];
    }
}

// ---------------- MLP head + softmax: LDS-resident weights, 4 nodes/wave ----------------
__global__ __launch_bounds__(256, 2) void mlp_k(const float* __restrict__ emb,
                      const float* __restrict__ Wm1, const float* __restrict__ bm1,
                      const float* __restrict__ Wm2, const float* __restrict__ bm2,
                      float* __restrict__ sout){
    __shared__ float W1a[64][64];
    __shared__ float W1b[64][64];
    __shared__ float W2t[16][132];
    __shared__ float b1s[128];
    __shared__ float b2s[16];
    __shared__ float semb[4][64][4];
    __shared__ float shid[4][4][132];

    int tx = threadIdx.x;
    for (int i = tx; i < 64 * 64; i += 256){
        int c = i >> 6, l = i & 63;
        W1a[c][l] = Wm1[c * 128 + l];
        W1b[c][l] = Wm1[c * 128 + 64 + l];
    }
    for (int i = tx; i < 16 * 128; i += 256){
        int k = i >> 7, j = i & 127;
        W2t[k][j] = Wm2[j * NK + k];
    }
    if (tx < 128) b1s[tx] = bm1[tx];
    if (tx < 16)  b2s[tx] = bm2[tx];
    __syncthreads();

    int lane = tx & 63, wid = tx >> 6;
    int k16 = lane & 15, ni = lane >> 4;

    for (int base = blockIdx.x * 16; base < NNODES; base += gridDim.x * 16){
        int d0 = base + wid * 4;
#pragma unroll
        for (int i = 0; i < 4; i++)
            semb[wid][lane][i] = emb[(size_t)(d0 + i) * OUTC + lane];
        __syncthreads();

        float2 acc[4];
#pragma unroll
        for (int i = 0; i < 4; i++) acc[i] = make_float2(b1s[lane], b1s[64 + lane]);
#pragma unroll 8
        for (int c = 0; c < 64; c++){
            float wa = W1a[c][lane];
            float wb = W1b[c][lane];
            float4 e = *(const float4*)&semb[wid][c][0];
            acc[0].x += e.x * wa; acc[0].y += e.x * wb;
            acc[1].x += e.y * wa; acc[1].y += e.y * wb;
            acc[2].x += e.z * wa; acc[2].y += e.z * wb;
            acc[3].x += e.w * wa; acc[3].y += e.w * wb;
        }
#pragma unroll
        for (int i = 0; i < 4; i++){
            shid[wid][i][lane]      = fmaxf(acc[i].x, 0.f);
            shid[wid][i][64 + lane] = fmaxf(acc[i].y, 0.f);
        }
        __syncthreads();

        float lg = b2s[k16];
        const float* hp = &shid[wid][ni][0];
        const float* wp = &W2t[k16][0];
#pragma unroll 8
        for (int j = 0; j < 128; j++) lg += hp[j] * wp[j];

        float m = lg;
        for (int msk = 1; msk < NK; msk <<= 1) m = fmaxf(m, __shfl_xor(m, msk, NK));
        float ex = expf(lg - m);
        float s = ex;
        for (int msk = 1; msk < NK; msk <<= 1) s += __shfl_xor(s, msk, NK);
        sout[(size_t)(d0 + ni) * NK + k16] = ex / s;
    }
}

// ---------------- launcher ----------------
extern "C" void kernel_launch(void* const* d_in, const int* in_sizes, int n_in,
                              void* d_out, int out_size, void* d_ws, size_t ws_size,
                              hipStream_t stream){
    const float* x      = (const float*)d_in[0];
    const int*   ei     = (const int*)d_in[1];
    const int*   srcv   = ei;
    const int*   dstv   = ei + NEDGES;
    const float* W1     = (const float*)d_in[2];
    const float* att_s1 = (const float*)d_in[3];
    const float* att_d1 = (const float*)d_in[4];
    const float* b1     = (const float*)d_in[5];
    const float* W2     = (const float*)d_in[6];
    const float* att_s2 = (const float*)d_in[7];
    const float* att_d2 = (const float*)d_in[8];
    const float* b2     = (const float*)d_in[9];
    const float* Wm1    = (const float*)d_in[10];
    const float* bm1    = (const float*)d_in[11];
    const float* Wm2    = (const float*)d_in[12];
    const float* bm2    = (const float*)d_in[13];

    float* out     = (float*)d_out;                     // s: [N,16]
    float* emb_out = out + (size_t)NNODES * NK;         // embeddings: [N,64]

    u16* h1b   = (u16*)d_ws;                            // N*256
    u16* hL1b  = h1b  + (size_t)NNODES * HC1;           // N*256
    u16* h2b   = hL1b + (size_t)NNODES * HC1;           // N*64
    u16* W1t   = h2b  + (size_t)NNODES * OUTC;          // 256*128
    u16* W2t   = W1t + 256 * 128;                       // 64*256
    float* as1 = (float*)(W2t + 64 * 256);              // N*8
    float* ad1 = as1 + (size_t)NNODES * NHEADS;         // N*8
    float* as2 = ad1 + (size_t)NNODES * NHEADS;         // N
    float* ad2 = as2 + NNODES;                          // N
    int* deg    = (int*)(ad2 + NNODES);                 // N
    int* rowptr = deg + NNODES;                         // N+1
    int* bsum   = rowptr + NNODES + 1;                  // 256
    int* boff   = bsum + 256;                           // 256
    int* fillc  = boff + 256;                           // N
    int* colv   = fillc + NNODES;                       // E

    hipMemsetAsync(deg, 0, NNODES * sizeof(int), stream);
    hipMemsetAsync(fillc, 0, NNODES * sizeof(int), stream);

    const int NB = (NNODES + 255) / 256;
    count_deg_k<<<(NEDGES + 255) / 256, 256, 0, stream>>>(dstv, deg);
    blocksum_k<<<NB, 256, 0, stream>>>(deg, bsum);
    scan_bsum_k<<<1, 256, 0, stream>>>(bsum, boff, NB);
    scan_write_k<<<NB, 256, 0, stream>>>(deg, boff, rowptr);
    fill_csr_k<<<(NEDGES + 255) / 256, 256, 0, stream>>>(srcv, dstv, rowptr, fillc, colv);

    transpose_w1_k<<<128, 256, 0, stream>>>(W1, W1t);
    transpose_w2_k<<<64, 256, 0, stream>>>(W2, W2t);

    const int MB = (NNODES + 63) / 64;   // 782

    l1_k<<<MB, 256, 0, stream>>>(x, W1t, att_s1, att_d1, h1b, as1, ad1);
    gat1_agg_k<<<NNODES / 4, 256, 0, stream>>>(h1b, as1, ad1, rowptr, colv, b1, hL1b);

    l2_k<<<MB, 256, 0, stream>>>(hL1b, W2t, att_s2, att_d2, h2b, as2, ad2);
    gat2_agg_k<<<NNODES / 4, 256, 0, stream>>>(h2b, as2, ad2, rowptr, colv, b2, emb_out);

    mlp_k<<<512, 256, 0, stream>>>(emb_out, Wm1, bm1, Wm2, bm2, out);
}

// Round 8
// 328.062 us; speedup vs baseline: 1.2615x; 1.0035x over previous
//
#include <hip/hip_runtime.h>
#include <math.h>

#define NNODES 50000
#define NEDGES 400000
#define INC    128
#define HC1    256   // HEADS*HID
#define NHEADS 8
#define OUTC   64
#define NK     16
#define NEG_SLOPE 0.2f
#define EPS_F  1e-16f

typedef unsigned short u16;
typedef __attribute__((ext_vector_type(8))) short bf16x8;
typedef __attribute__((ext_vector_type(4))) float f32x4;

__device__ __forceinline__ float lrelu(float x){ return x > 0.f ? x : NEG_SLOPE * x; }
__device__ __forceinline__ float eluf(float x){ return x > 0.f ? x : (expf(x) - 1.f); }
__device__ __forceinline__ float bf2f(u16 v){ return __uint_as_float((unsigned)v << 16); }
__device__ __forceinline__ u16 f2bf(float f){
    unsigned u = __float_as_uint(f);
    unsigned r = (u + 0x7FFFu + ((u >> 16) & 1u)) >> 16;   // RTNE
    return (u16)r;
}
__device__ __forceinline__ short f2bf_s(float f){ return (short)f2bf(f); }

// ---------------- CSR build ----------------
__global__ void count_deg_k(const int* __restrict__ dst, int* __restrict__ deg){
    int e = blockIdx.x * 256 + threadIdx.x;
    if (e < NEDGES) atomicAdd(&deg[dst[e]], 1);
}

__global__ void blocksum_k(const int* __restrict__ deg, int* __restrict__ bsum){
    __shared__ int sm[4];
    int i = blockIdx.x * 256 + threadIdx.x;
    int v = (i < NNODES) ? deg[i] : 0;
    for (int off = 1; off < 64; off <<= 1) v += __shfl_xor(v, off);
    int lane = threadIdx.x & 63, wid = threadIdx.x >> 6;
    if (lane == 0) sm[wid] = v;
    __syncthreads();
    if (threadIdx.x == 0) bsum[blockIdx.x] = sm[0] + sm[1] + sm[2] + sm[3];
}

__global__ void scan_bsum_k(const int* __restrict__ bsum, int* __restrict__ boff, int nb){
    int tid = threadIdx.x;
    int v = (tid < nb) ? bsum[tid] : 0;
    int orig = v;
    int lane = tid & 63, wid = tid >> 6;
    for (int off = 1; off < 64; off <<= 1){ int t = __shfl_up(v, off); if (lane >= off) v += t; }
    __shared__ int wsum[4];
    if (lane == 63) wsum[wid] = v;
    __syncthreads();
    int add = 0;
    for (int w = 0; w < wid; w++) add += wsum[w];
    v += add;
    if (tid < nb) boff[tid] = v - orig;
}

__global__ void scan_write_k(const int* __restrict__ deg, const int* __restrict__ boff,
                             int* __restrict__ rowptr){
    int tid = threadIdx.x;
    int i = blockIdx.x * 256 + tid;
    int v = (i < NNODES) ? deg[i] : 0;
    int lane = tid & 63, wid = tid >> 6;
    int sv = v;
    for (int off = 1; off < 64; off <<= 1){ int t = __shfl_up(sv, off); if (lane >= off) sv += t; }
    __shared__ int wsum[4];
    if (lane == 63) wsum[wid] = sv;
    __syncthreads();
    int add = 0;
    for (int w = 0; w < wid; w++) add += wsum[w];
    sv += add;
    if (i < NNODES) rowptr[i + 1] = boff[blockIdx.x] + sv;
    if (i == 0) rowptr[0] = 0;
}

__global__ void fill_csr_k(const int* __restrict__ src, const int* __restrict__ dst,
                           const int* __restrict__ rowptr, int* __restrict__ fillc,
                           int* __restrict__ col){
    int e = blockIdx.x * 256 + threadIdx.x;
    if (e < NEDGES){
        int d = dst[e];
        int pos = atomicAdd(&fillc[d], 1);
        col[rowptr[d] + pos] = src[e];
    }
}

// ---------------- weight transposes (fp32 -> bf16, [N][K]) ----------------
__global__ void transpose_w1_k(const float* __restrict__ W, u16* __restrict__ Wt){
    int i = blockIdx.x * 256 + threadIdx.x;   // 32768
    int n = i >> 7, k = i & 127;
    Wt[i] = f2bf(W[k * 256 + n]);
}

__global__ void transpose_w2_k(const float* __restrict__ W, u16* __restrict__ Wt){
    int i = blockIdx.x * 256 + threadIdx.x;   // 16384
    int n = i >> 8, k = i & 255;
    Wt[i] = f2bf(W[k * 64 + n]);
}

// ---------------- L1: h1b[N,256] = bf16(x) @ W1, fused att1 ----------------
__global__ void l1_k(const float* __restrict__ x, const u16* __restrict__ W1t,
                     const float* __restrict__ att_s, const float* __restrict__ att_d,
                     u16* __restrict__ h1b, float* __restrict__ as1, float* __restrict__ ad1){
    int lane = threadIdx.x & 63, wid = threadIdx.x >> 6;
    int ln = lane & 15, quad = lane >> 4;
    int m0 = blockIdx.x * 64 + wid * 16;
    int arow = m0 + ln; if (arow >= NNODES) arow = NNODES - 1;

    bf16x8 a[4];
#pragma unroll
    for (int kt = 0; kt < 4; kt++){
        const float* ap = x + (size_t)arow * INC + kt * 32 + quad * 8;
        float4 v0 = *(const float4*)ap;
        float4 v1 = *(const float4*)(ap + 4);
        bf16x8 t;
        t[0] = f2bf_s(v0.x); t[1] = f2bf_s(v0.y); t[2] = f2bf_s(v0.z); t[3] = f2bf_s(v0.w);
        t[4] = f2bf_s(v1.x); t[5] = f2bf_s(v1.y); t[6] = f2bf_s(v1.z); t[7] = f2bf_s(v1.w);
        a[kt] = t;
    }

    f32x4 acc[16];
#pragma unroll
    for (int nt = 0; nt < 16; nt++) acc[nt] = (f32x4){0.f, 0.f, 0.f, 0.f};

#pragma unroll
    for (int kt = 0; kt < 4; kt++){
#pragma unroll
        for (int nt = 0; nt < 16; nt++){
            bf16x8 b = *(const bf16x8*)(W1t + (size_t)(nt * 16 + ln) * INC + kt * 32 + quad * 8);
            acc[nt] = __builtin_amdgcn_mfma_f32_16x16x32_bf16(a[kt], b, acc[nt], 0, 0, 0);
        }
    }

#pragma unroll
    for (int i = 0; i < 4; i++){
        int r = m0 + quad * 4 + i;
        if (r < NNODES){
#pragma unroll
            for (int nt = 0; nt < 16; nt++)
                h1b[(size_t)r * HC1 + nt * 16 + ln] = f2bf(acc[nt][i]);
        }
    }

#pragma unroll
    for (int i = 0; i < 4; i++){
        int r = m0 + quad * 4 + i;
        float ps_keep = 0.f, pd_keep = 0.f;
#pragma unroll
        for (int h = 0; h < 8; h++){
            float ps = acc[2 * h][i]     * att_s[h * 32 + ln]
                     + acc[2 * h + 1][i] * att_s[h * 32 + 16 + ln];
            float pd = acc[2 * h][i]     * att_d[h * 32 + ln]
                     + acc[2 * h + 1][i] * att_d[h * 32 + 16 + ln];
            ps += __shfl_xor(ps, 1); pd += __shfl_xor(pd, 1);
            ps += __shfl_xor(ps, 2); pd += __shfl_xor(pd, 2);
            ps += __shfl_xor(ps, 4); pd += __shfl_xor(pd, 4);
            ps += __shfl_xor(ps, 8); pd += __shfl_xor(pd, 8);
            if (ln == h){ ps_keep = ps; pd_keep = pd; }
        }
        if (ln < 8 && r < NNODES){
            as1[r * NHEADS + ln] = ps_keep;
            ad1[r * NHEADS + ln] = pd_keep;
        }
    }
}

// ---------------- L2: h2b[N,64] = hL1b @ W2, fused att2 ----------------
__global__ void l2_k(const u16* __restrict__ hL1b, const u16* __restrict__ W2t,
                     const float* __restrict__ att_s, const float* __restrict__ att_d,
                     u16* __restrict__ h2b, float* __restrict__ as2, float* __restrict__ ad2){
    int lane = threadIdx.x & 63, wid = threadIdx.x >> 6;
    int ln = lane & 15, quad = lane >> 4;
    int m0 = blockIdx.x * 64 + wid * 16;
    int arow = m0 + ln; if (arow >= NNODES) arow = NNODES - 1;

    f32x4 acc[4];
#pragma unroll
    for (int nt = 0; nt < 4; nt++) acc[nt] = (f32x4){0.f, 0.f, 0.f, 0.f};

#pragma unroll
    for (int kt = 0; kt < 8; kt++){
        bf16x8 a = *(const bf16x8*)(hL1b + (size_t)arow * HC1 + kt * 32 + quad * 8);
#pragma unroll
        for (int nt = 0; nt < 4; nt++){
            bf16x8 b = *(const bf16x8*)(W2t + (size_t)(nt * 16 + ln) * HC1 + kt * 32 + quad * 8);
            acc[nt] = __builtin_amdgcn_mfma_f32_16x16x32_bf16(a, b, acc[nt], 0, 0, 0);
        }
    }

#pragma unroll
    for (int i = 0; i < 4; i++){
        int r = m0 + quad * 4 + i;
        if (r < NNODES){
#pragma unroll
            for (int nt = 0; nt < 4; nt++)
                h2b[(size_t)r * OUTC + nt * 16 + ln] = f2bf(acc[nt][i]);
        }
        float ps = acc[0][i] * att_s[ln]      + acc[1][i] * att_s[16 + ln]
                 + acc[2][i] * att_s[32 + ln] + acc[3][i] * att_s[48 + ln];
        float pd = acc[0][i] * att_d[ln]      + acc[1][i] * att_d[16 + ln]
                 + acc[2][i] * att_d[32 + ln] + acc[3][i] * att_d[48 + ln];
        ps += __shfl_xor(ps, 1); pd += __shfl_xor(pd, 1);
        ps += __shfl_xor(ps, 2); pd += __shfl_xor(pd, 2);
        ps += __shfl_xor(ps, 4); pd += __shfl_xor(pd, 4);
        ps += __shfl_xor(ps, 8); pd += __shfl_xor(pd, 8);
        if (ln == 0 && r < NNODES){ as2[r] = ps; ad2[r] = pd; }
    }
}

// ---------------- GAT layer 1 aggregation v4 ----------------
// deg<=64: col + unnormalized-exp cached in registers across phases; phase 3 loads ONLY h1b.
// Lane layouts and formulas identical to R7 (known-good).
__global__ void gat1_agg_k(const u16* __restrict__ h1b, const float* __restrict__ as1,
                           const float* __restrict__ ad1, const int* __restrict__ rowptr,
                           const int* __restrict__ col, const float* __restrict__ b1,
                           u16* __restrict__ outb){
    int lane = threadIdx.x & 63, wid = threadIdx.x >> 6;
    int d = blockIdx.x * 4 + wid;
    int row0 = rowptr[d];
    int deg  = rowptr[d + 1] - row0;

    int h8 = lane & 7, j = lane >> 3;
    float adst      = ad1[d * NHEADS + h8];
    float asrc_self = as1[d * NHEADS + h8];
    float e_self = lrelu(asrc_self + adst);

    if (deg <= 64){
        int nch = (deg + 7) >> 3;
        int cv[8]; float ex[8];
        // phase 1: cache col + e, running max  (lane = j*8+h8 handles edge c*8+j, head h8)
        float vmax = e_self;
#pragma unroll
        for (int c = 0; c < 8; c++){
            if (c >= nch) break;
            int idx = c * 8 + j;
            cv[c] = (idx < deg) ? col[row0 + idx] : d;
            if (idx < deg){
                float e = lrelu(as1[cv[c] * NHEADS + h8] + adst);
                ex[c] = e;
                vmax = fmaxf(vmax, e);
            } else ex[c] = -3e38f;
        }
        vmax = fmaxf(vmax, __shfl_xor(vmax, 8));
        vmax = fmaxf(vmax, __shfl_xor(vmax, 16));
        vmax = fmaxf(vmax, __shfl_xor(vmax, 32));

        // phase 2: in-register exp + sum
        float vsum = (j == 0) ? expf(e_self - vmax) : 0.f;
#pragma unroll
        for (int c = 0; c < 8; c++){
            if (c >= nch) break;
            float t = (ex[c] > -1e37f) ? expf(ex[c] - vmax) : 0.f;
            ex[c] = t;
            vsum += t;
        }
        vsum += __shfl_xor(vsum, 8);
        vsum += __shfl_xor(vsum, 16);
        vsum += __shfl_xor(vsum, 32);
        float rden = 1.f / (vsum + EPS_F);
        float exn = 0.f;   // normalized alpha in-register
#pragma unroll
        for (int c = 0; c < 8; c++){ if (c >= nch) break; }
        // (normalize lazily inside shfl below to keep regs minimal)

        // phase 3: half-wave per edge; lane covers channels l32*8.. ; head hd = l32>>2
        int hw = lane >> 5, l32 = lane & 31, hd = l32 >> 2;
        float sa_reg = expf(e_self - vmax) * rden;
        float sa_b   = __shfl(sa_reg, hd);
        float asf    = hw ? 0.f : sa_b;
        (void)exn;

        float acc[8];
        {
            uint4 w = *(const uint4*)(h1b + (size_t)d * HC1 + l32 * 8);
            acc[0] = asf * __uint_as_float(w.x << 16);
            acc[1] = asf * __uint_as_float(w.x & 0xFFFF0000u);
            acc[2] = asf * __uint_as_float(w.y << 16);
            acc[3] = asf * __uint_as_float(w.y & 0xFFFF0000u);
            acc[4] = asf * __uint_as_float(w.z << 16);
            acc[5] = asf * __uint_as_float(w.z & 0xFFFF0000u);
            acc[6] = asf * __uint_as_float(w.w << 16);
            acc[7] = asf * __uint_as_float(w.w & 0xFFFF0000u);
        }

#pragma unroll
        for (int c = 0; c < 8; c++){
            if (c >= nch) break;
            float an = ex[c] * rden;   // lane (j,h8): alpha(edge c*8+j, head h8); 0 if padded
#pragma unroll
            for (int st = 0; st < 4; st++){
                int it = st * 2 + hw;
                int s  = __shfl(cv[c], it * 8);
                float a = __shfl(an, it * 8 + hd);
                uint4 w = *(const uint4*)(h1b + (size_t)s * HC1 + l32 * 8);
                acc[0] += a * __uint_as_float(w.x << 16);
                acc[1] += a * __uint_as_float(w.x & 0xFFFF0000u);
                acc[2] += a * __uint_as_float(w.y << 16);
                acc[3] += a * __uint_as_float(w.y & 0xFFFF0000u);
                acc[4] += a * __uint_as_float(w.z << 16);
                acc[5] += a * __uint_as_float(w.z & 0xFFFF0000u);
                acc[6] += a * __uint_as_float(w.w << 16);
                acc[7] += a * __uint_as_float(w.w & 0xFFFF0000u);
            }
        }
#pragma unroll
        for (int k = 0; k < 8; k++) acc[k] += __shfl_xor(acc[k], 32);

        if (lane < 32){
            float4 b0 = *(const float4*)(b1 + l32 * 8);
            float4 b4 = *(const float4*)(b1 + l32 * 8 + 4);
            uint4 o;
            o.x = (unsigned)f2bf(eluf(acc[0] + b0.x)) | ((unsigned)f2bf(eluf(acc[1] + b0.y)) << 16);
            o.y = (unsigned)f2bf(eluf(acc[2] + b0.z)) | ((unsigned)f2bf(eluf(acc[3] + b0.w)) << 16);
            o.z = (unsigned)f2bf(eluf(acc[4] + b4.x)) | ((unsigned)f2bf(eluf(acc[5] + b4.y)) << 16);
            o.w = (unsigned)f2bf(eluf(acc[6] + b4.z)) | ((unsigned)f2bf(eluf(acc[7] + b4.w)) << 16);
            *(uint4*)(outb + (size_t)d * HC1 + l32 * 8) = o;
        }
    } else {
        // legacy path (R7, load-based), any degree
        float vmax = e_self;
        for (int base = 0; base < deg; base += 8){
            int idx = base + j;
            if (idx < deg){
                int s = col[row0 + idx];
                vmax = fmaxf(vmax, lrelu(as1[s * NHEADS + h8] + adst));
            }
        }
        vmax = fmaxf(vmax, __shfl_xor(vmax, 8));
        vmax = fmaxf(vmax, __shfl_xor(vmax, 16));
        vmax = fmaxf(vmax, __shfl_xor(vmax, 32));

        float vsum = (j == 0) ? expf(e_self - vmax) : 0.f;
        for (int base = 0; base < deg; base += 8){
            int idx = base + j;
            if (idx < deg){
                int s = col[row0 + idx];
                vsum += expf(lrelu(as1[s * NHEADS + h8] + adst) - vmax);
            }
        }
        vsum += __shfl_xor(vsum, 8);
        vsum += __shfl_xor(vsum, 16);
        vsum += __shfl_xor(vsum, 32);
        float rden = 1.f / (vsum + EPS_F);

        int hw = lane >> 5, l32 = lane & 31, hd = l32 >> 2;
        float sa_reg = expf(e_self - vmax) * rden;
        float sa_b   = __shfl(sa_reg, hd);
        float asf    = hw ? 0.f : sa_b;

        float acc[8];
        {
            uint4 w = *(const uint4*)(h1b + (size_t)d * HC1 + l32 * 8);
            acc[0] = asf * __uint_as_float(w.x << 16);
            acc[1] = asf * __uint_as_float(w.x & 0xFFFF0000u);
            acc[2] = asf * __uint_as_float(w.y << 16);
            acc[3] = asf * __uint_as_float(w.y & 0xFFFF0000u);
            acc[4] = asf * __uint_as_float(w.z << 16);
            acc[5] = asf * __uint_as_float(w.z & 0xFFFF0000u);
            acc[6] = asf * __uint_as_float(w.w << 16);
            acc[7] = asf * __uint_as_float(w.w & 0xFFFF0000u);
        }

        for (int base = 0; base < deg; base += 8){
            int eidx = base + j;
            int cj = (eidx < deg) ? col[row0 + eidx] : d;
            float ae = (eidx < deg)
                     ? expf(lrelu(as1[cj * NHEADS + h8] + adst) - vmax) * rden : 0.f;
#pragma unroll
            for (int st = 0; st < 4; st++){
                int it = st * 2 + hw;
                int s  = __shfl(cj, it * 8);
                float a = __shfl(ae, it * 8 + hd);
                uint4 w = *(const uint4*)(h1b + (size_t)s * HC1 + l32 * 8);
                acc[0] += a * __uint_as_float(w.x << 16);
                acc[1] += a * __uint_as_float(w.x & 0xFFFF0000u);
                acc[2] += a * __uint_as_float(w.y << 16);
                acc[3] += a * __uint_as_float(w.y & 0xFFFF0000u);
                acc[4] += a * __uint_as_float(w.z << 16);
                acc[5] += a * __uint_as_float(w.z & 0xFFFF0000u);
                acc[6] += a * __uint_as_float(w.w << 16);
                acc[7] += a * __uint_as_float(w.w & 0xFFFF0000u);
            }
        }
#pragma unroll
        for (int k = 0; k < 8; k++) acc[k] += __shfl_xor(acc[k], 32);

        if (lane < 32){
            float4 b0 = *(const float4*)(b1 + l32 * 8);
            float4 b4 = *(const float4*)(b1 + l32 * 8 + 4);
            uint4 o;
            o.x = (unsigned)f2bf(eluf(acc[0] + b0.x)) | ((unsigned)f2bf(eluf(acc[1] + b0.y)) << 16);
            o.y = (unsigned)f2bf(eluf(acc[2] + b0.z)) | ((unsigned)f2bf(eluf(acc[3] + b0.w)) << 16);
            o.z = (unsigned)f2bf(eluf(acc[4] + b4.x)) | ((unsigned)f2bf(eluf(acc[5] + b4.y)) << 16);
            o.w = (unsigned)f2bf(eluf(acc[6] + b4.z)) | ((unsigned)f2bf(eluf(acc[7] + b4.w)) << 16);
            *(uint4*)(outb + (size_t)d * HC1 + l32 * 8) = o;
        }
    }
}

// ---------------- GAT layer 2 aggregation v3 (quarter-wave per edge) ----------------
__global__ void gat2_agg_k(const u16* __restrict__ h2b, const float* __restrict__ as2,
                           const float* __restrict__ ad2, const int* __restrict__ rowptr,
                           const int* __restrict__ col, const float* __restrict__ b2,
                           float* __restrict__ emb){
    int lane = threadIdx.x & 63, wid = threadIdx.x >> 6;
    int d = blockIdx.x * 4 + wid;
    int row0 = rowptr[d];
    int deg  = rowptr[d + 1] - row0;

    float adst = ad2[d];
    float e_self = lrelu(as2[d] + adst);

    if (deg <= 64){
        int sv = (lane < deg) ? col[row0 + lane] : d;
        float e_lane = (lane < deg) ? lrelu(as2[sv] + adst) : -3e38f;
        float vmax = fmaxf(e_self, e_lane);
        for (int m = 1; m < 64; m <<= 1) vmax = fmaxf(vmax, __shfl_xor(vmax, m));
        float exl = (lane < deg) ? expf(e_lane - vmax) : 0.f;
        float vsum = exl + ((lane == 0) ? expf(e_self - vmax) : 0.f);
        for (int m = 1; m < 64; m <<= 1) vsum += __shfl_xor(vsum, m);
        float rden = 1.f / (vsum + EPS_F);
        float alpha_l = exl * rden;
        float sa = expf(e_self - vmax) * rden;

        int q = lane >> 4, c4 = (lane & 15) * 4;
        float a0 = (q == 0) ? sa : 0.f;
        float4 acc;
        {
            ushort4 u = *(const ushort4*)(h2b + (size_t)d * OUTC + c4);
            acc = make_float4(a0 * bf2f(u.x), a0 * bf2f(u.y), a0 * bf2f(u.z), a0 * bf2f(u.w));
        }
        for (int it0 = 0; it0 < deg; it0 += 8){
#pragma unroll
            for (int k = 0; k < 2; k++){
                int it = it0 + k * 4 + q;
                int itc = min(it, 63);
                int s   = __shfl(sv, itc);
                float a = __shfl(alpha_l, itc);
                ushort4 u = *(const ushort4*)(h2b + (size_t)s * OUTC + c4);
                acc.x += a * bf2f(u.x); acc.y += a * bf2f(u.y);
                acc.z += a * bf2f(u.z); acc.w += a * bf2f(u.w);
            }
        }
        acc.x += __shfl_xor(acc.x, 16); acc.y += __shfl_xor(acc.y, 16);
        acc.z += __shfl_xor(acc.z, 16); acc.w += __shfl_xor(acc.w, 16);
        acc.x += __shfl_xor(acc.x, 32); acc.y += __shfl_xor(acc.y, 32);
        acc.z += __shfl_xor(acc.z, 32); acc.w += __shfl_xor(acc.w, 32);
        if (lane < 16){
            float4 bb = *(const float4*)(b2 + c4);
            float4 o = make_float4(acc.x + bb.x, acc.y + bb.y, acc.z + bb.z, acc.w + bb.w);
            *(float4*)(emb + (size_t)d * OUTC + c4) = o;
        }
    } else {
        float vmax = e_self;
        for (int base = 0; base < deg; base += 64){
            int idx = base + lane;
            if (idx < deg){
                int s = col[row0 + idx];
                vmax = fmaxf(vmax, lrelu(as2[s] + adst));
            }
        }
        for (int m = 1; m < 64; m <<= 1) vmax = fmaxf(vmax, __shfl_xor(vmax, m));
        float vsum = (lane == 0) ? expf(e_self - vmax) : 0.f;
        for (int base = 0; base < deg; base += 64){
            int idx = base + lane;
            if (idx < deg){
                int s = col[row0 + idx];
                vsum += expf(lrelu(as2[s] + adst) - vmax);
            }
        }
        for (int m = 1; m < 64; m <<= 1) vsum += __shfl_xor(vsum, m);
        float rden = 1.f / (vsum + EPS_F);
        float alpha = expf(e_self - vmax) * rden;
        float acc = alpha * bf2f(h2b[(size_t)d * OUTC + lane]);
        for (int idx = 0; idx < deg; idx++){
            int s = col[row0 + idx];
            float a = expf(lrelu(as2[s] + adst) - vmax) * rden;
            acc += a * bf2f(h2b[(size_t)s * OUTC + lane]);
        }
        emb[(size_t)d * OUTC + lane] = acc + b2[lane];
    }
}

// ---------------- MLP head + softmax: LDS-resident weights, 4 nodes/wave ----------------
__global__ __launch_bounds__(256, 2) void mlp_k(const float* __restrict__ emb,
                      const float* __restrict__ Wm1, const float* __restrict__ bm1,
                      const float* __restrict__ Wm2, const float* __restrict__ bm2,
                      float* __restrict__ sout){
    __shared__ float W1a[64][64];
    __shared__ float W1b[64][64];
    __shared__ float W2t[16][132];
    __shared__ float b1s[128];
    __shared__ float b2s[16];
    __shared__ float semb[4][64][4];
    __shared__ float shid[4][4][132];

    int tx = threadIdx.x;
    for (int i = tx; i < 64 * 64; i += 256){
        int c = i >> 6, l = i & 63;
        W1a[c][l] = Wm1[c * 128 + l];
        W1b[c][l] = Wm1[c * 128 + 64 + l];
    }
    for (int i = tx; i < 16 * 128; i += 256){
        int k = i >> 7, j = i & 127;
        W2t[k][j] = Wm2[j * NK + k];
    }
    if (tx < 128) b1s[tx] = bm1[tx];
    if (tx < 16)  b2s[tx] = bm2[tx];
    __syncthreads();

    int lane = tx & 63, wid = tx >> 6;
    int k16 = lane & 15, ni = lane >> 4;

    for (int base = blockIdx.x * 16; base < NNODES; base += gridDim.x * 16){
        int d0 = base + wid * 4;
#pragma unroll
        for (int i = 0; i < 4; i++)
            semb[wid][lane][i] = emb[(size_t)(d0 + i) * OUTC + lane];
        __syncthreads();

        float2 acc[4];
#pragma unroll
        for (int i = 0; i < 4; i++) acc[i] = make_float2(b1s[lane], b1s[64 + lane]);
#pragma unroll 8
        for (int c = 0; c < 64; c++){
            float wa = W1a[c][lane];
            float wb = W1b[c][lane];
            float4 e = *(const float4*)&semb[wid][c][0];
            acc[0].x += e.x * wa; acc[0].y += e.x * wb;
            acc[1].x += e.y * wa; acc[1].y += e.y * wb;
            acc[2].x += e.z * wa; acc[2].y += e.z * wb;
            acc[3].x += e.w * wa; acc[3].y += e.w * wb;
        }
#pragma unroll
        for (int i = 0; i < 4; i++){
            shid[wid][i][lane]      = fmaxf(acc[i].x, 0.f);
            shid[wid][i][64 + lane] = fmaxf(acc[i].y, 0.f);
        }
        __syncthreads();

        float lg = b2s[k16];
        const float* hp = &shid[wid][ni][0];
        const float* wp = &W2t[k16][0];
#pragma unroll 8
        for (int j = 0; j < 128; j++) lg += hp[j] * wp[j];

        float m = lg;
        for (int msk = 1; msk < NK; msk <<= 1) m = fmaxf(m, __shfl_xor(m, msk, NK));
        float ex = expf(lg - m);
        float s = ex;
        for (int msk = 1; msk < NK; msk <<= 1) s += __shfl_xor(s, msk, NK);
        sout[(size_t)(d0 + ni) * NK + k16] = ex / s;
    }
}

// ---------------- launcher ----------------
extern "C" void kernel_launch(void* const* d_in, const int* in_sizes, int n_in,
                              void* d_out, int out_size, void* d_ws, size_t ws_size,
                              hipStream_t stream){
    const float* x      = (const float*)d_in[0];
    const int*   ei     = (const int*)d_in[1];
    const int*   srcv   = ei;
    const int*   dstv   = ei + NEDGES;
    const float* W1     = (const float*)d_in[2];
    const float* att_s1 = (const float*)d_in[3];
    const float* att_d1 = (const float*)d_in[4];
    const float* b1     = (const float*)d_in[5];
    const float* W2     = (const float*)d_in[6];
    const float* att_s2 = (const float*)d_in[7];
    const float* att_d2 = (const float*)d_in[8];
    const float* b2     = (const float*)d_in[9];
    const float* Wm1    = (const float*)d_in[10];
    const float* bm1    = (const float*)d_in[11];
    const float* Wm2    = (const float*)d_in[12];
    const float* bm2    = (const float*)d_in[13];

    float* out     = (float*)d_out;                     // s: [N,16]
    float* emb_out = out + (size_t)NNODES * NK;         // embeddings: [N,64]

    u16* h1b   = (u16*)d_ws;                            // N*256
    u16* hL1b  = h1b  + (size_t)NNODES * HC1;           // N*256
    u16* h2b   = hL1b + (size_t)NNODES * HC1;           // N*64
    u16* W1t   = h2b  + (size_t)NNODES * OUTC;          // 256*128
    u16* W2t   = W1t + 256 * 128;                       // 64*256
    float* as1 = (float*)(W2t + 64 * 256);              // N*8
    float* ad1 = as1 + (size_t)NNODES * NHEADS;         // N*8
    float* as2 = ad1 + (size_t)NNODES * NHEADS;         // N
    float* ad2 = as2 + NNODES;                          // N
    int* deg    = (int*)(ad2 + NNODES);                 // N
    int* rowptr = deg + NNODES;                         // N+1
    int* bsum   = rowptr + NNODES + 1;                  // 256
    int* boff   = bsum + 256;                           // 256
    int* fillc  = boff + 256;                           // N
    int* colv   = fillc + NNODES;                       // E

    hipMemsetAsync(deg, 0, NNODES * sizeof(int), stream);
    hipMemsetAsync(fillc, 0, NNODES * sizeof(int), stream);

    const int NB = (NNODES + 255) / 256;
    count_deg_k<<<(NEDGES + 255) / 256, 256, 0, stream>>>(dstv, deg);
    blocksum_k<<<NB, 256, 0, stream>>>(deg, bsum);
    scan_bsum_k<<<1, 256, 0, stream>>>(bsum, boff, NB);
    scan_write_k<<<NB, 256, 0, stream>>>(deg, boff, rowptr);
    fill_csr_k<<<(NEDGES + 255) / 256, 256, 0, stream>>>(srcv, dstv, rowptr, fillc, colv);

    transpose_w1_k<<<128, 256, 0, stream>>>(W1, W1t);
    transpose_w2_k<<<64, 256, 0, stream>>>(W2, W2t);

    const int MB = (NNODES + 63) / 64;   // 782

    l1_k<<<MB, 256, 0, stream>>>(x, W1t, att_s1, att_d1, h1b, as1, ad1);
    gat1_agg_k<<<NNODES / 4, 256, 0, stream>>>(h1b, as1, ad1, rowptr, colv, b1, hL1b);

    l2_k<<<MB, 256, 0, stream>>>(hL1b, W2t, att_s2, att_d2, h2b, as2, ad2);
    gat2_agg_k<<<NNODES / 4, 256, 0, stream>>>(h2b, as2, ad2, rowptr, colv, b2, emb_out);

    mlp_k<<<512, 256, 0, stream>>>(emb_out, Wm1, bm1, Wm2, bm2, out);
}